// Round 10
// baseline (2632.166 us; speedup 1.0000x reference)
//
#include <hip/hip_runtime.h>
#include <cstddef>
#include <cstdint>

constexpr int NB = 256;
constexpr int NT = 512;
constexpr int NV = 32;

typedef _Float16 h2_t __attribute__((ext_vector_type(2)));
typedef _Float16 f16x4v __attribute__((ext_vector_type(4)));
typedef _Float16 f16x8 __attribute__((ext_vector_type(8)));
typedef float f32x4 __attribute__((ext_vector_type(4)));

__device__ __forceinline__ float sigmoidf_(float x){ return 1.0f/(1.0f+__expf(-x)); }
__device__ __forceinline__ float tanhf_(float x){ return 1.0f - 2.0f/(__expf(2.0f*x)+1.0f); }

__device__ __forceinline__ uint32_t pack2u_(float a, float b){
  h2_t r; r.x=(_Float16)a; r.y=(_Float16)b; return __builtin_bit_cast(uint32_t, r);
}
__device__ __forceinline__ float dot2u_(uint32_t u, uint32_t w, float c){
#if __has_builtin(__builtin_amdgcn_fdot2)
  return __builtin_amdgcn_fdot2(__builtin_bit_cast(h2_t,u), __builtin_bit_cast(h2_t,w), c, false);
#else
  h2_t a=__builtin_bit_cast(h2_t,u), b=__builtin_bit_cast(h2_t,w);
  return c + (float)a.x*(float)b.x + (float)a.y*(float)b.y;
#endif
}
__device__ __forceinline__ float h2f_(unsigned short u){
  _Float16 hv = __builtin_bit_cast(_Float16, u); return (float)hv;
}
__device__ __forceinline__ unsigned short f2h_(float a){
  _Float16 hv = (_Float16)a; return __builtin_bit_cast(unsigned short, hv);
}

// ---------------- stats + x_comp ----------------
__global__ __launch_bounds__(256) void k_stats(
    const float* __restrict__ values, const float* __restrict__ masks,
    const int* __restrict__ lengths,
    float* __restrict__ x_comp, float* __restrict__ stats)
{
  const int b = blockIdx.x;
  const int v = threadIdx.x & 31;
  const int g = threadIdx.x >> 5;
  const int len = lengths[b];
  const float* vb = values + (size_t)b*NT*NV;
  const float* mb = masks  + (size_t)b*NT*NV;
  float* xb = x_comp + (size_t)b*NT*NV;
  float s_m=0.f, s_mv=0.f, s_v=0.f, s_v2=0.f;
  for (int t=g; t<NT; t+=8){
    float val = vb[t*NV+v];
    float m   = mb[t*NV+v];
    float xp  = (t==0) ? vb[v] : vb[(t-1)*NV+v];
    float pm  = (t<len) ? 1.0f : 0.0f;
    xb[t*NV+v] = (m*val + (1.0f-m)*xp)*pm;
    s_m += m; s_mv += m*val; s_v += val; s_v2 += val*val;
  }
  __shared__ float red[4][8][32];
  red[0][g][v]=s_m; red[1][g][v]=s_mv; red[2][g][v]=s_v; red[3][g][v]=s_v2;
  __syncthreads();
  if (g==0){
    float a0=0,a1=0,a2=0,a3=0;
    #pragma unroll
    for(int i=0;i<8;i++){ a0+=red[0][i][v]; a1+=red[1][i][v]; a2+=red[2][i][v]; a3+=red[3][i][v]; }
    float msum = fmaxf(a0, 1.0f);
    float mean = a1/msum;
    float dss  = a3 - 2.0f*mean*a2 + (float)NT*mean*mean;
    float var  = (msum > 1.0f) ? dss/(msum-1.0f) : 0.0f;
    float sd   = sqrtf(fmaxf(var, 0.0f));
    float miss = 1.0f - a0 / fmaxf((float)len, 1.0f);
    float* st = stats + b*97;
    if (v==0) st[0] = (float)len;
    st[1+v]=mean; st[33+v]=sd; st[65+v]=miss;
  }
}

// ---------------- context MLP ----------------
__global__ __launch_bounds__(64) void k_cmlp(
    const float* __restrict__ stats,
    const float* __restrict__ W1, const float* __restrict__ b1,
    const float* __restrict__ W2, const float* __restrict__ b2,
    float* __restrict__ ctx)
{
  const int b = blockIdx.x;
  const int j = threadIdx.x;
  __shared__ float st[97];
  __shared__ float hm[64];
  for (int k=j; k<97; k+=64) st[k] = stats[b*97+k];
  __syncthreads();
  float a0=b1[j], a1=0.f, a2=0.f, a3=0.f;
  #pragma unroll
  for (int k=0; k<96; k+=4){
    a0 += st[k]*W1[j*97+k];     a1 += st[k+1]*W1[j*97+k+1];
    a2 += st[k+2]*W1[j*97+k+2]; a3 += st[k+3]*W1[j*97+k+3];
  }
  a0 += st[96]*W1[j*97+96];
  hm[j] = fmaxf((a0+a1)+(a2+a3), 0.0f);
  __syncthreads();
  if (j < 32){
    float c0_=b2[j], c1=0.f, c2=0.f, c3=0.f;
    #pragma unroll
    for (int k=0;k<64;k+=4){
      c0_ += hm[k]*W2[j*64+k];    c1 += hm[k+1]*W2[j*64+k+1];
      c2 += hm[k+2]*W2[j*64+k+2]; c3 += hm[k+3]*W2[j*64+k+3];
    }
    ctx[b*64+j] = (c0_+c1)+(c2+c3);
  }
}

// ---------------- GRU x-part GEMM -> gig2[bg][t][n][96] f16 ----------------
__global__ __launch_bounds__(128) void k_gigru(
    const float* __restrict__ x_comp, const float* __restrict__ rain_f,
    const float* __restrict__ rain_b,
    const float* __restrict__ Wih, const float* __restrict__ bih,
    unsigned short* __restrict__ gig)
{
  __shared__ uint32_t WT[48][98];
  __shared__ __align__(16) uint32_t us[8][48];
  const int tid = threadIdx.x;
  for (int idx = tid; idx < 48*96; idx += 128){
    const int k = idx / 96, col = idx - k*96;
    WT[k][col] = pack2u_(Wih[(size_t)col*96 + 2*k], Wih[(size_t)col*96 + 2*k + 1]);
  }
  const float bias = (tid < 96) ? bih[tid] : 0.f;
  __syncthreads();
  const int NR = NB*NT;
  for (int r0 = blockIdx.x*8; r0 < NR; r0 += gridDim.x*8){
    __syncthreads();
    for (int idx = tid; idx < 8*48; idx += 128){
      const int r = idx / 48, w = idx - r*48;
      const size_t row = (size_t)r0 + r;
      const int i0 = 2*w, i1 = 2*w+1;
      const float a = (i0<32)? x_comp[row*32+i0] : (i0<64 ? rain_f[row*32+i0-32] : rain_b[row*32+i0-64]);
      const float c = (i1<32)? x_comp[row*32+i1] : (i1<64 ? rain_f[row*32+i1-32] : rain_b[row*32+i1-64]);
      us[r][w] = pack2u_(a, c);
    }
    __syncthreads();
    if (tid < 96){
      #pragma unroll
      for (int r=0;r<8;r++){
        const uint4* U = (const uint4*)us[r];
        float acc = bias;
        #pragma unroll
        for (int k4=0;k4<12;k4++){
          const uint4 u4 = U[k4];
          acc = dot2u_(u4.x, WT[4*k4][tid],   acc);
          acc = dot2u_(u4.y, WT[4*k4+1][tid], acc);
          acc = dot2u_(u4.z, WT[4*k4+2][tid], acc);
          acc = dot2u_(u4.w, WT[4*k4+3][tid], acc);
        }
        const size_t row = (size_t)r0 + r;
        const int bb = (int)(row >> 9), tt = (int)(row & 511);
        gig[(((size_t)(bb>>4)*NT + tt)*16 + (bb&15))*96 + tid] = f2h_(acc);
      }
    }
  }
}

// ---------------- GRU scan: MFMA over 16 batches/block ----------------
// M=96 gates, K=32 (h), N=16 batches. 128 threads = 2 waves, wave w owns m-tiles 3w..3w+2.
__global__ __launch_bounds__(128) void k_gru(
    const unsigned short* __restrict__ gig2, const int* __restrict__ lengths,
    const float* __restrict__ Whh, const float* __restrict__ bhh,
    float* __restrict__ ctx)
{
  __shared__ __align__(16) _Float16 Ahg[6*4*16*8];   // [mt][s][r][i]
  __shared__ __align__(16) _Float16 Hpk[4*16*8];     // [s][n][i]
  __shared__ __align__(16) float glds[6*16*16];      // [mt][n][row]
  __shared__ __align__(16) float bhl[96];
  __shared__ int lensh[16];
  const int bg = blockIdx.x, b0 = bg*16;
  const int tid = threadIdx.x, wv = tid>>6, lane = tid&63;
  const int fr = lane>>4, fc = lane&15;
  for (int idx=tid; idx<96*32; idx+=128){
    const int g = idx>>5, k = idx&31;
    Ahg[(((g>>4)*4 + (k>>3))*16 + (g&15))*8 + (k&7)] = (_Float16)Whh[g*32+k];
  }
  if (tid<96) bhl[tid] = bhh[tid];
  if (tid<16) lensh[tid] = lengths[b0+tid];
  for (int idx=tid; idx<512; idx+=128) Hpk[idx] = (_Float16)0.f;
  __syncthreads();
  int lmax = 0;
  #pragma unroll
  for (int i=0;i<16;i++) lmax = max(lmax, lensh[i]);
  if (lmax > NT) lmax = NT;
  const int e = tid&31, ng = tid>>5;
  float hreg[4] = {0.f,0.f,0.f,0.f};
  int len4[4];
  #pragma unroll
  for (int q=0;q<4;q++) len4[q] = lensh[4*ng+q];
  const size_t gbase = (size_t)bg*NT*16*96;
  const int mt0 = 3*wv;
  f16x4v s0v = {}, s1v = {}, s2v = {};
  float gin4[4] = {0.f,0.f,0.f,0.f};
  if (lmax > 0){
    const size_t tb = gbase;
    s0v = *(const f16x4v*)&gig2[tb + (size_t)fc*96 + (mt0  )*16 + fr*4];
    if (mt0+1 < 4) s1v = *(const f16x4v*)&gig2[tb + (size_t)fc*96 + (mt0+1)*16 + fr*4];
    if (mt0+2 < 4) s2v = *(const f16x4v*)&gig2[tb + (size_t)fc*96 + (mt0+2)*16 + fr*4];
    #pragma unroll
    for (int q=0;q<4;q++) gin4[q] = h2f_(gig2[tb + (size_t)(4*ng+q)*96 + 64 + e]);
  }
  for (int t=0; t<lmax; ++t){
    f16x4v n0v = {}, n1v = {}, n2v = {};
    float ginn[4] = {0.f,0.f,0.f,0.f};
    const bool dp = (t+1 < lmax);
    if (dp){
      const size_t tb = gbase + (size_t)(t+1)*16*96;
      n0v = *(const f16x4v*)&gig2[tb + (size_t)fc*96 + (mt0  )*16 + fr*4];
      if (mt0+1 < 4) n1v = *(const f16x4v*)&gig2[tb + (size_t)fc*96 + (mt0+1)*16 + fr*4];
      if (mt0+2 < 4) n2v = *(const f16x4v*)&gig2[tb + (size_t)fc*96 + (mt0+2)*16 + fr*4];
      #pragma unroll
      for (int q=0;q<4;q++) ginn[q] = h2f_(gig2[tb + (size_t)(4*ng+q)*96 + 64 + e]);
    }
    const f16x8 bh = *(const f16x8*)&Hpk[(fr*16+fc)*8];
    #pragma unroll
    for (int j=0;j<3;j++){
      const int mt = mt0 + j;
      f32x4 acc = *(const f32x4*)&bhl[mt*16 + fr*4];
      if (mt < 4){
        const f16x4v sv = (j==0) ? s0v : ((j==1) ? s1v : s2v);
        acc.x += (float)sv.x; acc.y += (float)sv.y;
        acc.z += (float)sv.z; acc.w += (float)sv.w;
      }
      const f16x8 a = *(const f16x8*)&Ahg[((mt*4 + fr)*16 + fc)*8];
      acc = __builtin_amdgcn_mfma_f32_16x16x32_f16(a, bh, acc, 0, 0, 0);
      *(f32x4*)&glds[(mt*16+fc)*16 + fr*4] = acc;
    }
    __syncthreads();
    #pragma unroll
    for (int q=0;q<4;q++){
      const int n = 4*ng + q;
      const int mte = e>>4, re = e&15;
      const float rp = glds[((mte  )*16+n)*16 + re];
      const float zp = glds[((mte+2)*16+n)*16 + re];
      const float np = glds[((mte+4)*16+n)*16 + re];
      const float r = sigmoidf_(rp), z = sigmoidf_(zp);
      const float nn = tanhf_(gin4[q] + r*np);
      if (t < len4[q]) hreg[q] = (1.0f - z)*nn + z*hreg[q];
      Hpk[((e>>3)*16 + n)*8 + (e&7)] = (_Float16)hreg[q];
      gin4[q] = ginn[q];
    }
    s0v = n0v; s1v = n1v; s2v = n2v;
    __syncthreads();
  }
  #pragma unroll
  for (int q=0;q<4;q++) ctx[(size_t)(b0+4*ng+q)*64 + 32 + e] = hreg[q];
}

// ---------------- init: h0/c0, ctx-part of LSTM gates, hidden seeds ----------------
__global__ __launch_bounds__(256) void k_init(
    const float* __restrict__ ctx,
    const float* __restrict__ initW, const float* __restrict__ initb,
    const float* __restrict__ WihF, const float* __restrict__ bihF, const float* __restrict__ bhhF,
    const float* __restrict__ WihB, const float* __restrict__ bihB, const float* __restrict__ bhhB,
    float* __restrict__ h0, float* __restrict__ c0,
    float* __restrict__ cgF, float* __restrict__ cgB,
    float* __restrict__ hidden)
{
  const int b = blockIdx.x;
  const int j = threadIdx.x;
  __shared__ __align__(16) float cv[64];
  if (j < 64) cv[j] = ctx[b*64+j];
  __syncthreads();
  {
    float4 f = {bihF[j]+bhhF[j], 0.f, 0.f, 0.f};
    float4 g = {bihB[j]+bhhB[j], 0.f, 0.f, 0.f};
    #pragma unroll
    for (int q=0;q<16;q++){
      const float4 cvv = *(const float4*)&cv[4*q];
      const float4 wf = *(const float4*)(WihF + (size_t)j*128 + 64 + 4*q);
      const float4 wb = *(const float4*)(WihB + (size_t)j*128 + 64 + 4*q);
      f.x += cvv.x*wf.x; f.y += cvv.y*wf.y; f.z += cvv.z*wf.z; f.w += cvv.w*wf.w;
      g.x += cvv.x*wb.x; g.y += cvv.y*wb.y; g.z += cvv.z*wb.z; g.w += cvv.w*wb.w;
    }
    cgF[b*256+j] = (f.x+f.y)+(f.z+f.w);
    cgB[b*256+j] = (g.x+g.y)+(g.z+g.w);
  }
  if (j < 128){
    float4 a = {initb[j], 0.f, 0.f, 0.f};
    #pragma unroll
    for (int q=0;q<16;q++){
      const float4 cvv = *(const float4*)&cv[4*q];
      const float4 w  = *(const float4*)(initW + (size_t)j*64 + 4*q);
      a.x += cvv.x*w.x; a.y += cvv.y*w.y; a.z += cvv.z*w.z; a.w += cvv.w*w.w;
    }
    float hv = (a.x+a.y)+(a.z+a.w);
    h0[b*128+j] = hv;
    c0[b*128+j] = tanhf_(hv);
    if (j < 64) hidden[(size_t)b*NT*128 + j] = hv;                                // fwd seed t=0
    else        hidden[(size_t)b*NT*128 + (size_t)(NT-1)*128 + 64 + (j-64)] = hv; // bwd seed t=T-1
  }
}

// ---------------- LSTM scan: MFMA over 16 batches/block ----------------
// M=256 gates, K=64 (x|mask and h), N=16 batches. 256 threads = 4 waves; wave w owns m-tiles 4w..4w+3.
// dyn LDS: Ax 32KB | Ah 32KB | cgT 16KB | glds 16KB | Upk 4KB | Hpk 2KB = 104448 B
__global__ __launch_bounds__(256) void k_lstm(
    const float* __restrict__ x_comp, const float* __restrict__ masks,
    const float* __restrict__ WihF, const float* __restrict__ WhhF,
    const float* __restrict__ WihB, const float* __restrict__ WhhB,
    const float* __restrict__ cgF, const float* __restrict__ cgB,
    const float* __restrict__ h0, const float* __restrict__ c0,
    float* __restrict__ hidden)
{
  extern __shared__ char sm_[];
  _Float16* Ax  = (_Float16*)sm_;               // [16mt][2kt][4s][16r][8i]
  _Float16* Ah  = (_Float16*)(sm_ + 32768);
  float*    cgT = (float*)(sm_ + 65536);        // [16mt][16n][16row]
  float*    glds= (float*)(sm_ + 81920);        // [16mt][16n][16row]
  _Float16* Upk = (_Float16*)(sm_ + 98304);     // [2buf][2kt][4s][16n][8i]
  _Float16* Hpk = (_Float16*)(sm_ + 102400);    // [2kt][4s][16n][8i]
  const int bg = blockIdx.x, dir = blockIdx.y;
  const int b0 = bg*16;
  const int tid = threadIdx.x;
  const int wv = tid>>6, lane = tid&63;
  const int fr = lane>>4, fc = lane&15;
  const float* Wih = dir ? WihB : WihF;
  const float* Whh = dir ? WhhB : WhhF;
  const float* cgp = dir ? cgB : cgF;
  for (int idx = tid; idx < 16384; idx += 256){
    const int g = idx>>6, k = idx&63;
    const int off = ((((g>>4)*2 + (k>>5))*4 + ((k&31)>>3))*16 + (g&15))*8 + (k&7);
    Ax[off] = (_Float16)Wih[(size_t)g*128 + k];
    Ah[off] = (_Float16)Whh[(size_t)g*64  + k];
  }
  for (int idx = tid; idx < 4096; idx += 256){
    const int mt = idx>>8, n = (idx>>4)&15, r = idx&15;
    cgT[(mt*16+n)*16 + r] = cgp[(size_t)(b0+n)*256 + mt*16 + r];
  }
  const int e = tid&63, ng = tid>>6;
  float cst[4];
  #pragma unroll
  for (int q=0;q<4;q++){
    const int n = 4*ng+q;
    const float hv = h0[(size_t)(b0+n)*128 + dir*64 + e];
    cst[q]         = c0[(size_t)(b0+n)*128 + dir*64 + e];
    Hpk[(((e>>5)*4 + ((e&31)>>3))*16 + n)*8 + (e&7)] = (_Float16)hv;
  }
  const int un = tid&15, k4 = (tid>>4)*4;
  const int uoff = (((k4>>5)*4 + ((k4&31)>>3))*16 + un)*8 + (k4&7);
  {
    const int t0 = dir ? NT-1 : 0;
    const float* src = (k4 < 32) ? (x_comp + ((size_t)(b0+un)*NT + t0)*32 + k4)
                                 : (masks  + ((size_t)(b0+un)*NT + t0)*32 + (k4-32));
    const float4 v = *(const float4*)src;
    f16x4v pv; pv.x=(_Float16)v.x; pv.y=(_Float16)v.y; pv.z=(_Float16)v.z; pv.w=(_Float16)v.w;
    *(f16x4v*)&Upk[uoff] = pv;
  }
  __syncthreads();
  for (int s=0; s<NT-1; ++s){
    const int cur = s & 1;
    float4 pre = {0.f,0.f,0.f,0.f};
    const bool dp = (s+1 < NT-1);
    if (dp){
      const int tn = dir ? (NT-2-s) : (s+1);
      const float* src = (k4 < 32) ? (x_comp + ((size_t)(b0+un)*NT + tn)*32 + k4)
                                   : (masks  + ((size_t)(b0+un)*NT + tn)*32 + (k4-32));
      pre = *(const float4*)src;
    }
    const _Float16* Ub = Upk + cur*1024;
    const f16x8 bu0 = *(const f16x8*)&Ub[((0*4+fr)*16+fc)*8];
    const f16x8 bu1 = *(const f16x8*)&Ub[((1*4+fr)*16+fc)*8];
    const f16x8 bh0 = *(const f16x8*)&Hpk[((0*4+fr)*16+fc)*8];
    const f16x8 bh1 = *(const f16x8*)&Hpk[((1*4+fr)*16+fc)*8];
    #pragma unroll
    for (int j=0;j<4;j++){
      const int mt = 4*wv + j;
      f32x4 acc = *(const f32x4*)&cgT[(mt*16+fc)*16 + fr*4];
      const f16x8 ax0 = *(const f16x8*)&Ax[(((mt*2+0)*4 + fr)*16 + fc)*8];
      const f16x8 ax1 = *(const f16x8*)&Ax[(((mt*2+1)*4 + fr)*16 + fc)*8];
      acc = __builtin_amdgcn_mfma_f32_16x16x32_f16(ax0, bu0, acc, 0, 0, 0);
      acc = __builtin_amdgcn_mfma_f32_16x16x32_f16(ax1, bu1, acc, 0, 0, 0);
      const f16x8 ah0 = *(const f16x8*)&Ah[(((mt*2+0)*4 + fr)*16 + fc)*8];
      const f16x8 ah1 = *(const f16x8*)&Ah[(((mt*2+1)*4 + fr)*16 + fc)*8];
      acc = __builtin_amdgcn_mfma_f32_16x16x32_f16(ah0, bh0, acc, 0, 0, 0);
      acc = __builtin_amdgcn_mfma_f32_16x16x32_f16(ah1, bh1, acc, 0, 0, 0);
      *(f32x4*)&glds[(mt*16+fc)*16 + fr*4] = acc;
    }
    __syncthreads();
    const int outt = dir ? (NT-2-s) : (s+1);
    #pragma unroll
    for (int q=0;q<4;q++){
      const int n = 4*ng + q;
      const int mte = e>>4, re = e&15;
      const float gi = glds[((mte   )*16 + n)*16 + re];
      const float gf = glds[((mte+4 )*16 + n)*16 + re];
      const float gg = glds[((mte+8 )*16 + n)*16 + re];
      const float go = glds[((mte+12)*16 + n)*16 + re];
      cst[q] = sigmoidf_(gf)*cst[q] + sigmoidf_(gi)*tanhf_(gg);
      const float hh = sigmoidf_(go)*tanhf_(cst[q]);
      hidden[((size_t)(b0+n)*NT + outt)*128 + dir*64 + e] = hh;
      Hpk[(((e>>5)*4 + ((e&31)>>3))*16 + n)*8 + (e&7)] = (_Float16)hh;
    }
    if (dp){
      f16x4v pv; pv.x=(_Float16)pre.x; pv.y=(_Float16)pre.y; pv.z=(_Float16)pre.z; pv.w=(_Float16)pre.w;
      *(f16x4v*)&Upk[(cur^1)*1024 + uoff] = pv;
    }
    __syncthreads();
  }
}

// ---------------- feature-regression: LDS f16 weights, 4 rows/iter ----------------
__global__ __launch_bounds__(512) void k_feat(
    const float* __restrict__ x_comp,
    const float* __restrict__ feat_W, const float* __restrict__ feat_b,
    const float* __restrict__ nl1_W, const float* __restrict__ nl1_b,
    const float* __restrict__ nl2_W, const float* __restrict__ nl2_b,
    float* __restrict__ feat_imp)
{
  extern __shared__ char smem_[];
  uint32_t (*WfT)[1024]   = (uint32_t(*)[1024])(smem_);
  uint32_t (*nl1T)[32]    = (uint32_t(*)[32])(smem_ + 65536);
  uint32_t (*xp)[16]      = (uint32_t(*)[16])(smem_ + 67584);
  uint32_t (*hidp)[32][16]= (uint32_t(*)[32][16])(smem_ + 67840);
  const int tid = threadIdx.x;
  const int lane = tid & 31;
  const int ig = tid >> 5;        // 0..15
  const int i0 = ig, i1 = ig + 16;
  for (int idx = tid; idx < 16*1024; idx += 512){
    const int k = idx >> 10, rr = idx & 1023;
    const int i = rr >> 5;
    float a = feat_W[(size_t)rr*32 + 2*k];
    float c2 = feat_W[(size_t)rr*32 + 2*k + 1];
    if (2*k == i) a = 0.f;
    if (2*k+1 == i) c2 = 0.f;
    WfT[k][rr] = pack2u_(a, c2);
  }
  for (int idx = tid; idx < 16*32; idx += 512){
    const int k = idx >> 5, g = idx & 31;
    nl1T[k][g] = pack2u_(nl1_W[g*32 + 2*k], nl1_W[g*32 + 2*k + 1]);
  }
  const float fb0 = feat_b[i0*32 + lane];
  const float fb1 = feat_b[i1*32 + lane];
  const float n1b = nl1_b[lane];
  const float n2w = nl2_W[lane];
  const float n2b = nl2_b[0];
  __syncthreads();
  const int NQ = (NB*NT)/4;
  for (int rq = blockIdx.x; rq < NQ; rq += gridDim.x){
    const int r = rq*4;
    if (tid < 128){
      const int qq = tid >> 5, v = tid & 31;
      const float xv = x_comp[(size_t)(r+qq)*32 + v];
      const float pr = __shfl_xor(xv, 1);
      if (!(v & 1)) xp[qq][v>>1] = pack2u_(xv, pr);
    }
    __syncthreads();
    uint32_t wa[16], wb[16];
    #pragma unroll
    for (int k=0;k<16;k++){ wa[k] = WfT[k][i0*32+lane]; wb[k] = WfT[k][i1*32+lane]; }
    float za[4], zb[4];
    #pragma unroll
    for (int qq=0;qq<4;qq++){
      const uint4* xq = (const uint4*)xp[qq];
      const uint4 X0=xq[0], X1=xq[1], X2=xq[2], X3=xq[3];
      float s0 = fb0, s1 = fb1;
      s0=dot2u_(X0.x,wa[0],s0);  s1=dot2u_(X0.x,wb[0],s1);
      s0=dot2u_(X0.y,wa[1],s0);  s1=dot2u_(X0.y,wb[1],s1);
      s0=dot2u_(X0.z,wa[2],s0);  s1=dot2u_(X0.z,wb[2],s1);
      s0=dot2u_(X0.w,wa[3],s0);  s1=dot2u_(X0.w,wb[3],s1);
      s0=dot2u_(X1.x,wa[4],s0);  s1=dot2u_(X1.x,wb[4],s1);
      s0=dot2u_(X1.y,wa[5],s0);  s1=dot2u_(X1.y,wb[5],s1);
      s0=dot2u_(X1.z,wa[6],s0);  s1=dot2u_(X1.z,wb[6],s1);
      s0=dot2u_(X1.w,wa[7],s0);  s1=dot2u_(X1.w,wb[7],s1);
      s0=dot2u_(X2.x,wa[8],s0);  s1=dot2u_(X2.x,wb[8],s1);
      s0=dot2u_(X2.y,wa[9],s0);  s1=dot2u_(X2.y,wb[9],s1);
      s0=dot2u_(X2.z,wa[10],s0); s1=dot2u_(X2.z,wb[10],s1);
      s0=dot2u_(X2.w,wa[11],s0); s1=dot2u_(X2.w,wb[11],s1);
      s0=dot2u_(X3.x,wa[12],s0); s1=dot2u_(X3.x,wb[12],s1);
      s0=dot2u_(X3.y,wa[13],s0); s1=dot2u_(X3.y,wb[13],s1);
      s0=dot2u_(X3.z,wa[14],s0); s1=dot2u_(X3.z,wb[14],s1);
      s0=dot2u_(X3.w,wa[15],s0); s1=dot2u_(X3.w,wb[15],s1);
      za[qq] = fmaxf(s0, 0.f); zb[qq] = fmaxf(s1, 0.f);
    }
    #pragma unroll
    for (int qq=0;qq<4;qq++){
      const float pa = __shfl_xor(za[qq], 1);
      const float pb = __shfl_xor(zb[qq], 1);
      if (!(lane & 1)){
        hidp[qq][i0][lane>>1] = pack2u_(za[qq], pa);
        hidp[qq][i1][lane>>1] = pack2u_(zb[qq], pb);
      }
    }
    __syncthreads();
    uint32_t nw[16];
    #pragma unroll
    for (int k=0;k<16;k++) nw[k] = nl1T[k][lane];
    float o[8];
    #pragma unroll
    for (int qq=0;qq<4;qq++){
      const uint4* h0p = (const uint4*)hidp[qq][i0];
      const uint4* h1p = (const uint4*)hidp[qq][i1];
      float s0 = n1b, s1 = n1b;
      #pragma unroll
      for (int c4=0;c4<4;c4++){
        const uint4 H0 = h0p[c4];
        const uint4 H1 = h1p[c4];
        s0=dot2u_(H0.x,nw[4*c4],s0);   s1=dot2u_(H1.x,nw[4*c4],s1);
        s0=dot2u_(H0.y,nw[4*c4+1],s0); s1=dot2u_(H1.y,nw[4*c4+1],s1);
        s0=dot2u_(H0.z,nw[4*c4+2],s0); s1=dot2u_(H1.z,nw[4*c4+2],s1);
        s0=dot2u_(H0.w,nw[4*c4+3],s0); s1=dot2u_(H1.w,nw[4*c4+3],s1);
      }
      o[2*qq]   = fmaxf(s0,0.f)*n2w;
      o[2*qq+1] = fmaxf(s1,0.f)*n2w;
    }
    #pragma unroll
    for (int m=0;m<8;m++){
      #pragma unroll
      for (int off=16; off>0; off>>=1) o[m] += __shfl_xor(o[m], off, 32);
    }
    if (lane == 0){
      #pragma unroll
      for (int qq=0;qq<4;qq++){
        feat_imp[(size_t)(r+qq)*32 + i0] = o[2*qq]   + n2b;
        feat_imp[(size_t)(r+qq)*32 + i1] = o[2*qq+1] + n2b;
      }
    }
    __syncthreads();
  }
}

// ---------------- rnn_imp GEMM + fuse + final: LDS f16 rimp ----------------
__global__ __launch_bounds__(512) void k_final(
    const float* __restrict__ values, const float* __restrict__ masks,
    const float* __restrict__ feat_imp, const float* __restrict__ hidden,
    const float* __restrict__ rimp_W, const float* __restrict__ rimp_b,
    const float* __restrict__ fuse_W, const float* __restrict__ fuse_b,
    const int* __restrict__ lengths, float* __restrict__ out)
{
  const int tid = threadIdx.x;
  const int v = tid & 31;
  const int grp = (tid >> 5) & 7;
  const int half = tid >> 8;
  __shared__ uint32_t rpT[64][32];
  __shared__ __align__(16) uint32_t hrowp[8][64];
  __shared__ float rpart[8][32];
  __shared__ float bpart[8][32];
  for (int idx = tid; idx < 64*32; idx += 512){
    const int k = idx >> 5, vv = idx & 31;
    rpT[k][vv] = pack2u_(rimp_W[(size_t)vv*128 + 2*k], rimp_W[(size_t)vv*128 + 2*k+1]);
  }
  const float4* F4 = (const float4*)(fuse_W + (size_t)v*64 + 32);
  float fconst = 0.f;
  if (!half){
    fconst = fuse_b[v];
    #pragma unroll
    for (int q=0;q<8;q++){
      const float4 fw = *(const float4*)(fuse_W + (size_t)v*64 + 4*q);
      fconst += (fw.x+fw.y)+(fw.z+fw.w);
    }
  }
  const float rbias = rimp_b[v];
  __syncthreads();
  const int NOCT = (NB*NT)/8;
  for (int oc = blockIdx.x; oc < NOCT; oc += gridDim.x){
    const size_t base = (size_t)oc*8;
    __syncthreads();
    if (tid < 256){
      const float4 hv = ((const float4*)(hidden + base*128))[tid];
      const int row = tid >> 5;
      const int w0 = (tid & 31) << 1;
      hrowp[row][w0]   = pack2u_(hv.x, hv.y);
      hrowp[row][w0+1] = pack2u_(hv.z, hv.w);
    }
    __syncthreads();
    const size_t r = base + grp;
    float a = half ? 0.f : rbias;
    {
      const uint4* hp4 = (const uint4*)&hrowp[grp][half*32];
      #pragma unroll
      for (int c4=0;c4<8;c4++){
        const uint4 H = hp4[c4];
        a = dot2u_(H.x, rpT[half*32 + 4*c4][v],     a);
        a = dot2u_(H.y, rpT[half*32 + 4*c4 + 1][v], a);
        a = dot2u_(H.z, rpT[half*32 + 4*c4 + 2][v], a);
        a = dot2u_(H.w, rpT[half*32 + 4*c4 + 3][v], a);
      }
    }
    if (half){
      rpart[grp][v] = a;
      const float* mrow = masks + r*32;
      float m0=0,m1=0,m2=0,m3=0;
      #pragma unroll
      for (int q=0;q<8;q++){
        const float4 mv = *(const float4*)(mrow + 4*q);
        const float4 fv = F4[q];
        m0 = fmaf(mv.x, fv.x, m0); m1 = fmaf(mv.y, fv.y, m1);
        m2 = fmaf(mv.z, fv.z, m2); m3 = fmaf(mv.w, fv.w, m3);
      }
      bpart[grp][v] = (m0+m1)+(m2+m3);
    }
    __syncthreads();
    if (!half){
      const int bb = (int)(r >> 9);
      const int t  = (int)(r & 511);
      const int len = lengths[bb];
      const float rimp = a + rpart[grp][v];
      const float beta = sigmoidf_(fconst + bpart[grp][v]);
      const float fi = feat_imp[r*32+v];
      const float m  = masks[r*32+v];
      const float val= values[r*32+v];
      const float fz = beta*fi + (1.0f-beta)*rimp;
      const float o = m*val + (1.0f-m)*fz;
      out[r*32+v] = (t < len) ? o : 0.0f;
    }
  }
}

extern "C" void kernel_launch(void* const* d_in, const int* in_sizes, int n_in,
                              void* d_out, int out_size, void* d_ws, size_t ws_size,
                              hipStream_t stream) {
  const float* values   = (const float*)d_in[0];
  const float* masks    = (const float*)d_in[1];
  const float* rain_f   = (const float*)d_in[2];
  const float* rain_b   = (const float*)d_in[3];
  const float* cmlp_W1  = (const float*)d_in[4];
  const float* cmlp_b1  = (const float*)d_in[5];
  const float* cmlp_W2  = (const float*)d_in[6];
  const float* cmlp_b2  = (const float*)d_in[7];
  const float* gru_Wih  = (const float*)d_in[8];
  const float* gru_Whh  = (const float*)d_in[9];
  const float* gru_bih  = (const float*)d_in[10];
  const float* gru_bhh  = (const float*)d_in[11];
  const float* init_W   = (const float*)d_in[12];
  const float* init_b   = (const float*)d_in[13];
  const float* lstmf_Wih= (const float*)d_in[14];
  const float* lstmf_Whh= (const float*)d_in[15];
  const float* lstmf_bih= (const float*)d_in[16];
  const float* lstmf_bhh= (const float*)d_in[17];
  const float* lstmb_Wih= (const float*)d_in[18];
  const float* lstmb_Whh= (const float*)d_in[19];
  const float* lstmb_bih= (const float*)d_in[20];
  const float* lstmb_bhh= (const float*)d_in[21];
  const float* rimp_W   = (const float*)d_in[22];
  const float* rimp_b   = (const float*)d_in[23];
  const float* feat_W   = (const float*)d_in[24];
  const float* feat_b   = (const float*)d_in[25];
  const float* nl1_W    = (const float*)d_in[26];
  const float* nl1_b    = (const float*)d_in[27];
  const float* nl2_W    = (const float*)d_in[28];
  const float* nl2_b    = (const float*)d_in[29];
  const float* fuse_W   = (const float*)d_in[30];
  const float* fuse_b   = (const float*)d_in[31];
  const int*   lengths  = (const int*)d_in[32];
  float* out = (float*)d_out;

  float* ws       = (float*)d_ws;
  float* x_comp   = ws;                                   // B*T*V
  float* stats    = x_comp + (size_t)NB*NT*NV;            // B*97
  float* ctx      = stats + NB*97;                        // B*64
  float* h0       = ctx + NB*64;                          // B*128
  float* c0      = h0 + NB*128;                           // B*128
  float* cgF      = c0 + NB*128;                          // B*256
  float* cgB      = cgF + NB*256;                         // B*256
  float* hidden   = cgB + NB*256;                         // B*T*128
  float* feat_imp = hidden + (size_t)NB*NT*128;           // B*T*V
  unsigned short* gig = (unsigned short*)(feat_imp + (size_t)NB*NT*NV); // B*T*96 f16
  // total ~127 MB

  k_stats<<<NB, 256, 0, stream>>>(values, masks, lengths, x_comp, stats);
  k_gigru<<<1024, 128, 0, stream>>>(x_comp, rain_f, rain_b, gru_Wih, gru_bih, gig);
  k_cmlp<<<NB, 64, 0, stream>>>(stats, cmlp_W1, cmlp_b1, cmlp_W2, cmlp_b2, ctx);
  k_gru<<<NB/16, 128, 0, stream>>>(gig, lengths, gru_Whh, gru_bhh, ctx);
  k_init<<<NB, 256, 0, stream>>>(ctx, init_W, init_b,
                                 lstmf_Wih, lstmf_bih, lstmf_bhh,
                                 lstmb_Wih, lstmb_bih, lstmb_bhh,
                                 h0, c0, cgF, cgB, hidden);
  dim3 lgrid(NB/16, 2);
  k_lstm<<<lgrid, 256, 104448, stream>>>(x_comp, masks,
                                         lstmf_Wih, lstmf_Whh, lstmb_Wih, lstmb_Whh,
                                         cgF, cgB, h0, c0, hidden);
  k_feat<<<512, 512, 76032, stream>>>(x_comp, feat_W, feat_b, nl1_W, nl1_b, nl2_W, nl2_b, feat_imp);
  k_final<<<2048, 512, 0, stream>>>(values, masks, feat_imp, hidden,
                                    rimp_W, rimp_b, fuse_W, fuse_b, lengths, out);
}

// Round 11
// 1601.081 us; speedup vs baseline: 1.6440x; 1.6440x over previous
//
#include <hip/hip_runtime.h>
#include <cstddef>
#include <cstdint>

constexpr int NB = 256;
constexpr int NT = 512;
constexpr int NV = 32;

typedef _Float16 h2_t __attribute__((ext_vector_type(2)));

__device__ __forceinline__ float sigmoidf_(float x){ return 1.0f/(1.0f+__expf(-x)); }
__device__ __forceinline__ float tanhf_(float x){ return 1.0f - 2.0f/(__expf(2.0f*x)+1.0f); }

__device__ __forceinline__ uint32_t pack2u_(float a, float b){
  h2_t r; r.x=(_Float16)a; r.y=(_Float16)b; return __builtin_bit_cast(uint32_t, r);
}
__device__ __forceinline__ float dot2u_(uint32_t u, uint32_t w, float c){
#if __has_builtin(__builtin_amdgcn_fdot2)
  return __builtin_amdgcn_fdot2(__builtin_bit_cast(h2_t,u), __builtin_bit_cast(h2_t,w), c, false);
#else
  h2_t a=__builtin_bit_cast(h2_t,u), b=__builtin_bit_cast(h2_t,w);
  return c + (float)a.x*(float)b.x + (float)a.y*(float)b.y;
#endif
}
__device__ __forceinline__ float h2f_(unsigned short u){
  _Float16 hv = __builtin_bit_cast(_Float16, u); return (float)hv;
}
__device__ __forceinline__ unsigned short f2h_(float a){
  _Float16 hv = (_Float16)a; return __builtin_bit_cast(unsigned short, hv);
}

#define Q4(acc, Wv, Uv) { acc=dot2u_((Uv).x,(Wv).x,acc); acc=dot2u_((Uv).y,(Wv).y,acc); \
                          acc=dot2u_((Uv).z,(Wv).z,acc); acc=dot2u_((Uv).w,(Wv).w,acc); }

// ---------------- stats + x_comp ----------------
__global__ __launch_bounds__(256) void k_stats(
    const float* __restrict__ values, const float* __restrict__ masks,
    const int* __restrict__ lengths,
    float* __restrict__ x_comp, float* __restrict__ stats)
{
  const int b = blockIdx.x;
  const int v = threadIdx.x & 31;
  const int g = threadIdx.x >> 5;
  const int len = lengths[b];
  const float* vb = values + (size_t)b*NT*NV;
  const float* mb = masks  + (size_t)b*NT*NV;
  float* xb = x_comp + (size_t)b*NT*NV;
  float s_m=0.f, s_mv=0.f, s_v=0.f, s_v2=0.f;
  for (int t=g; t<NT; t+=8){
    float val = vb[t*NV+v];
    float m   = mb[t*NV+v];
    float xp  = (t==0) ? vb[v] : vb[(t-1)*NV+v];
    float pm  = (t<len) ? 1.0f : 0.0f;
    xb[t*NV+v] = (m*val + (1.0f-m)*xp)*pm;
    s_m += m; s_mv += m*val; s_v += val; s_v2 += val*val;
  }
  __shared__ float red[4][8][32];
  red[0][g][v]=s_m; red[1][g][v]=s_mv; red[2][g][v]=s_v; red[3][g][v]=s_v2;
  __syncthreads();
  if (g==0){
    float a0=0,a1=0,a2=0,a3=0;
    #pragma unroll
    for(int i=0;i<8;i++){ a0+=red[0][i][v]; a1+=red[1][i][v]; a2+=red[2][i][v]; a3+=red[3][i][v]; }
    float msum = fmaxf(a0, 1.0f);
    float mean = a1/msum;
    float dss  = a3 - 2.0f*mean*a2 + (float)NT*mean*mean;
    float var  = (msum > 1.0f) ? dss/(msum-1.0f) : 0.0f;
    float sd   = sqrtf(fmaxf(var, 0.0f));
    float miss = 1.0f - a0 / fmaxf((float)len, 1.0f);
    float* st = stats + b*97;
    if (v==0) st[0] = (float)len;
    st[1+v]=mean; st[33+v]=sd; st[65+v]=miss;
  }
}

// ---------------- context MLP ----------------
__global__ __launch_bounds__(64) void k_cmlp(
    const float* __restrict__ stats,
    const float* __restrict__ W1, const float* __restrict__ b1,
    const float* __restrict__ W2, const float* __restrict__ b2,
    float* __restrict__ ctx)
{
  const int b = blockIdx.x;
  const int j = threadIdx.x;
  __shared__ float st[97];
  __shared__ float hm[64];
  for (int k=j; k<97; k+=64) st[k] = stats[b*97+k];
  __syncthreads();
  float a0=b1[j], a1=0.f, a2=0.f, a3=0.f;
  #pragma unroll
  for (int k=0; k<96; k+=4){
    a0 += st[k]*W1[j*97+k];     a1 += st[k+1]*W1[j*97+k+1];
    a2 += st[k+2]*W1[j*97+k+2]; a3 += st[k+3]*W1[j*97+k+3];
  }
  a0 += st[96]*W1[j*97+96];
  hm[j] = fmaxf((a0+a1)+(a2+a3), 0.0f);
  __syncthreads();
  if (j < 32){
    float c0_=b2[j], c1=0.f, c2=0.f, c3=0.f;
    #pragma unroll
    for (int k=0;k<64;k+=4){
      c0_ += hm[k]*W2[j*64+k];    c1 += hm[k+1]*W2[j*64+k+1];
      c2 += hm[k+2]*W2[j*64+k+2]; c3 += hm[k+3]*W2[j*64+k+3];
    }
    ctx[b*64+j] = (c0_+c1)+(c2+c3);
  }
}

// ---------------- GRU x-part GEMM: gig[b*T][96] f16 ----------------
__global__ __launch_bounds__(128) void k_gigru(
    const float* __restrict__ x_comp, const float* __restrict__ rain_f,
    const float* __restrict__ rain_b,
    const float* __restrict__ Wih, const float* __restrict__ bih,
    unsigned short* __restrict__ gig)
{
  __shared__ uint32_t WT[48][98];
  __shared__ __align__(16) uint32_t us[8][48];
  const int tid = threadIdx.x;
  for (int idx = tid; idx < 48*96; idx += 128){
    const int k = idx / 96, col = idx - k*96;
    WT[k][col] = pack2u_(Wih[(size_t)col*96 + 2*k], Wih[(size_t)col*96 + 2*k + 1]);
  }
  const float bias = (tid < 96) ? bih[tid] : 0.f;
  __syncthreads();
  const int NR = NB*NT;
  for (int r0 = blockIdx.x*8; r0 < NR; r0 += gridDim.x*8){
    __syncthreads();
    for (int idx = tid; idx < 8*48; idx += 128){
      const int r = idx / 48, w = idx - r*48;
      const size_t row = (size_t)r0 + r;
      const int i0 = 2*w, i1 = 2*w+1;
      const float a = (i0<32)? x_comp[row*32+i0] : (i0<64 ? rain_f[row*32+i0-32] : rain_b[row*32+i0-64]);
      const float c = (i1<32)? x_comp[row*32+i1] : (i1<64 ? rain_f[row*32+i1-32] : rain_b[row*32+i1-64]);
      us[r][w] = pack2u_(a, c);
    }
    __syncthreads();
    if (tid < 96){
      #pragma unroll
      for (int r=0;r<8;r++){
        const uint4* U = (const uint4*)us[r];
        float acc = bias;
        #pragma unroll
        for (int k4=0;k4<12;k4++){
          const uint4 u4 = U[k4];
          acc = dot2u_(u4.x, WT[4*k4][tid],   acc);
          acc = dot2u_(u4.y, WT[4*k4+1][tid], acc);
          acc = dot2u_(u4.z, WT[4*k4+2][tid], acc);
          acc = dot2u_(u4.w, WT[4*k4+3][tid], acc);
        }
        gig[((size_t)r0+r)*96 + tid] = f2h_(acc);
      }
    }
  }
}

// ---------------- GRU scan: 1 chain/block, grid 256, weights in LDS ----------------
__global__ __launch_bounds__(128) void k_gru(
    const unsigned short* __restrict__ gig, const int* __restrict__ lengths,
    const float* __restrict__ Whh, const float* __restrict__ bhh,
    float* __restrict__ ctx)
{
  __shared__ uint32_t Wg[96*20];     // row j: 16 packed words, stride 20 (80B, 16B-aligned)
  __shared__ __align__(16) uint32_t hp[16];
  __shared__ float gpart[96];
  const int b = blockIdx.x;
  const int tid = threadIdx.x;
  for (int idx = tid; idx < 96*16; idx += 128){
    const int row = idx >> 4, k = idx & 15;
    Wg[row*20+k] = pack2u_(Whh[row*32+2*k], Whh[row*32+2*k+1]);
  }
  const float bh = (tid < 96) ? bhh[tid] : 0.f;
  int len = lengths[b]; if (len > NT) len = NT;
  float h = 0.f;
  if (tid < 16) hp[tid] = 0u;
  const unsigned short* gp = gig + (size_t)b*NT*96;
  float gir=0.f, giz=0.f, gin=0.f;
  if (tid < 32 && len > 0){ gir=h2f_(gp[tid]); giz=h2f_(gp[32+tid]); gin=h2f_(gp[64+tid]); }
  __syncthreads();
  for (int t=0; t<len; ++t){
    float nr=0.f, nz=0.f, nn=0.f;
    if (tid < 32 && t+1 < len){
      const unsigned short* gn = gp + (size_t)(t+1)*96;
      nr=h2f_(gn[tid]); nz=h2f_(gn[32+tid]); nn=h2f_(gn[64+tid]);
    }
    if (tid < 96){
      const uint4* W4 = (const uint4*)(Wg + tid*20);
      const uint4 w0=W4[0], w1=W4[1], w2=W4[2], w3=W4[3];
      const uint4* H4 = (const uint4*)hp;
      const uint4 H0=H4[0], H1=H4[1], H2=H4[2], H3=H4[3];
      float acc = bh;
      Q4(acc,w0,H0) Q4(acc,w1,H1) Q4(acc,w2,H2) Q4(acc,w3,H3)
      gpart[tid] = acc;
    }
    __syncthreads();
    if (tid < 32){
      const float r = sigmoidf_(gir + gpart[tid]);
      const float z = sigmoidf_(giz + gpart[32+tid]);
      const float n = tanhf_(gin + r*gpart[64+tid]);
      h = (1.0f - z)*n + z*h;
      gir=nr; giz=nz; gin=nn;
      const float pr = __shfl_xor(h, 1);
      if (!(tid & 1)) hp[tid>>1] = pack2u_(h, pr);
    }
    __syncthreads();
  }
  if (tid < 32) ctx[b*64 + 32 + tid] = h;
}

// ---------------- init: h0/c0, ctx-part of LSTM gates, hidden seeds ----------------
__global__ __launch_bounds__(256) void k_init(
    const float* __restrict__ ctx,
    const float* __restrict__ initW, const float* __restrict__ initb,
    const float* __restrict__ WihF, const float* __restrict__ bihF, const float* __restrict__ bhhF,
    const float* __restrict__ WihB, const float* __restrict__ bihB, const float* __restrict__ bhhB,
    float* __restrict__ h0, float* __restrict__ c0,
    float* __restrict__ cgF, float* __restrict__ cgB,
    float* __restrict__ hidden)
{
  const int b = blockIdx.x;
  const int j = threadIdx.x;
  __shared__ __align__(16) float cv[64];
  if (j < 64) cv[j] = ctx[b*64+j];
  __syncthreads();
  {
    float4 f = {bihF[j]+bhhF[j], 0.f, 0.f, 0.f};
    float4 g = {bihB[j]+bhhB[j], 0.f, 0.f, 0.f};
    #pragma unroll
    for (int q=0;q<16;q++){
      const float4 cvv = *(const float4*)&cv[4*q];
      const float4 wf = *(const float4*)(WihF + (size_t)j*128 + 64 + 4*q);
      const float4 wb = *(const float4*)(WihB + (size_t)j*128 + 64 + 4*q);
      f.x += cvv.x*wf.x; f.y += cvv.y*wf.y; f.z += cvv.z*wf.z; f.w += cvv.w*wf.w;
      g.x += cvv.x*wb.x; g.y += cvv.y*wb.y; g.z += cvv.z*wb.z; g.w += cvv.w*wb.w;
    }
    cgF[b*256+j] = (f.x+f.y)+(f.z+f.w);
    cgB[b*256+j] = (g.x+g.y)+(g.z+g.w);
  }
  if (j < 128){
    float4 a = {initb[j], 0.f, 0.f, 0.f};
    #pragma unroll
    for (int q=0;q<16;q++){
      const float4 cvv = *(const float4*)&cv[4*q];
      const float4 w  = *(const float4*)(initW + (size_t)j*64 + 4*q);
      a.x += cvv.x*w.x; a.y += cvv.y*w.y; a.z += cvv.z*w.z; a.w += cvv.w*w.w;
    }
    float hv = (a.x+a.y)+(a.z+a.w);
    h0[b*128+j] = hv;
    c0[b*128+j] = tanhf_(hv);
    if (j < 64) hidden[(size_t)b*NT*128 + j] = hv;                                // fwd seed t=0
    else        hidden[(size_t)b*NT*128 + (size_t)(NT-1)*128 + 64 + (j-64)] = hv; // bwd seed t=T-1
  }
}

// ---------------- LSTM scan: 2 chains/block, weights in LDS, half-split ----------------
// 512 thr: row = half*256 + j. half0: Wih cols 0..63 (x|mask), half1: Whh (h).
// dyn LDS words: Wl[512*36]=18432 | u2[2][2][32]=128 | hp[2][32]=64 | gpart[2][2][256]=1024
//   total 19648 words = 78592 B
__global__ __launch_bounds__(512) void k_lstm(
    const float* __restrict__ x_comp, const float* __restrict__ masks,
    const float* __restrict__ WihF, const float* __restrict__ WhhF,
    const float* __restrict__ WihB, const float* __restrict__ WhhB,
    const float* __restrict__ cgF, const float* __restrict__ cgB,
    const float* __restrict__ h0, const float* __restrict__ c0,
    const int* __restrict__ lengths,
    float* __restrict__ hidden)
{
  extern __shared__ uint32_t lds[];
  uint32_t* Wl = lds;                 // [512][36]
  uint32_t* u2 = lds + 18432;         // [2buf][2c][32]
  uint32_t* hp = lds + 18560;         // [2c][32]
  float*  gpart = (float*)(lds + 18624); // [2half][2c][256]
  const int c0b = blockIdx.x*2;
  const int dir = blockIdx.y;
  const int tid = threadIdx.x;
  const int j = tid & 255;
  const int half = tid >> 8;
  const float* Wih = dir ? WihB : WihF;
  const float* Whh = dir ? WhhB : WhhF;
  for (int idx = tid; idx < 512*32; idx += 512){
    const int row = idx >> 5, k = idx & 31;
    float a, b2;
    if (row < 256){ a = Wih[(size_t)row*128 + 2*k]; b2 = Wih[(size_t)row*128 + 2*k+1]; }
    else          { a = Whh[(size_t)(row-256)*64 + 2*k]; b2 = Whh[(size_t)(row-256)*64 + 2*k+1]; }
    Wl[row*36 + k] = pack2u_(a, b2);
  }
  const float* cgp = (dir ? cgB : cgF);
  float cgc0 = 0.f, cgc1 = 0.f;
  if (!half){
    cgc0 = cgp[(size_t)(c0b+0)*256 + j];
    cgc1 = cgp[(size_t)(c0b+1)*256 + j];
  }
  const int len0 = lengths[c0b], len1 = lengths[c0b+1];
  int nsteps = NT-1;
  if (dir == 0){
    int e0 = len0-1; if (e0<0) e0=0;
    int e1 = len1-1; if (e1<0) e1=0;
    const int em = (e0>e1)?e0:e1;
    if (em < nsteps) nsteps = em;
  }
  // gate-phase state: tid<128, c = tid>>6, e = tid&63
  float cst = 0.f;
  if (tid < 128){
    const int c = tid>>6, e = tid&63;
    const float hv = h0[(size_t)(c0b+c)*128 + dir*64 + e];
    cst            = c0[(size_t)(c0b+c)*128 + dir*64 + e];
    const float pr = __shfl_xor(hv, 1);
    if (!(e & 1)) hp[c*32 + (e>>1)] = pack2u_(hv, pr);
  }
  // u2[0] stage: threads 384..511
  if (tid >= 384 && nsteps > 0){
    const int idx = tid - 384, c = idx>>6, u = idx&63;
    if (u < 32){
      const int t0 = dir ? NT-1 : 0;
      const float* src = (u < 16) ? (x_comp + ((size_t)(c0b+c)*NT + t0)*32 + 2*u)
                                  : (masks  + ((size_t)(c0b+c)*NT + t0)*32 + 2*u - 32);
      const float2 v = *(const float2*)src;
      u2[c*32 + u] = pack2u_(v.x, v.y);
    }
  }
  __syncthreads();
  for (int s=0; s<nsteps; ++s){
    const int cur = s & 1;
    float2 pre = {0.f, 0.f};
    int pc = 0, pu = 0;
    bool dopf = false;
    if (tid >= 384 && s+1 < nsteps){
      const int idx = tid - 384; pc = idx>>6; pu = idx&63;
      if (pu < 32){
        dopf = true;
        const int tn = dir ? (NT-2-s) : (s+1);
        const float* src = (pu < 16) ? (x_comp + ((size_t)(c0b+pc)*NT + tn)*32 + 2*pu)
                                     : (masks  + ((size_t)(c0b+pc)*NT + tn)*32 + 2*pu - 32);
        pre = *(const float2*)src;
      }
    }
    {
      const uint4* W4 = (const uint4*)(Wl + (size_t)(half*256 + j)*36);
      const uint4 w0=W4[0], w1=W4[1], w2=W4[2], w3=W4[3];
      const uint4 w4=W4[4], w5=W4[5], w6=W4[6], w7=W4[7];
      const uint32_t* ubase = half ? hp : (u2 + cur*64);
      // chain 0
      {
        const uint4* U = (const uint4*)(ubase + 0);
        const uint4 U0=U[0],U1=U[1],U2=U[2],U3=U[3],U4=U[4],U5=U[5],U6=U[6],U7=U[7];
        float acc = half ? 0.f : cgc0;
        Q4(acc,w0,U0) Q4(acc,w1,U1) Q4(acc,w2,U2) Q4(acc,w3,U3)
        Q4(acc,w4,U4) Q4(acc,w5,U5) Q4(acc,w6,U6) Q4(acc,w7,U7)
        gpart[half*512 + 0*256 + j] = acc;
      }
      // chain 1
      {
        const uint4* U = (const uint4*)(ubase + 32);
        const uint4 U0=U[0],U1=U[1],U2=U[2],U3=U[3],U4=U[4],U5=U[5],U6=U[6],U7=U[7];
        float acc = half ? 0.f : cgc1;
        Q4(acc,w0,U0) Q4(acc,w1,U1) Q4(acc,w2,U2) Q4(acc,w3,U3)
        Q4(acc,w4,U4) Q4(acc,w5,U5) Q4(acc,w6,U6) Q4(acc,w7,U7)
        gpart[half*512 + 1*256 + j] = acc;
      }
    }
    __syncthreads();
    if (tid < 128){
      const int c = tid>>6, e = tid&63;
      const float* gp0 = gpart + c*256;
      const float gi = gp0[e]       + gp0[512 + e];
      const float gf = gp0[64+e]    + gp0[512 + 64+e];
      const float gg = gp0[128+e]   + gp0[512 + 128+e];
      const float go = gp0[192+e]   + gp0[512 + 192+e];
      cst = sigmoidf_(gf)*cst + sigmoidf_(gi)*tanhf_(gg);
      const float hh = sigmoidf_(go)*tanhf_(cst);
      const int outt = dir ? (NT-2-s) : (s+1);
      hidden[((size_t)(c0b+c)*NT + outt)*128 + dir*64 + e] = hh;
      const float pr = __shfl_xor(hh, 1);
      if (!(e & 1)) hp[c*32 + (e>>1)] = pack2u_(hh, pr);
    }
    if (dopf) u2[(cur^1)*64 + pc*32 + pu] = pack2u_(pre.x, pre.y);
    __syncthreads();
  }
}

// ---------------- feature-regression: LDS f16 weights, 4 rows/iter ----------------
__global__ __launch_bounds__(512) void k_feat(
    const float* __restrict__ x_comp,
    const float* __restrict__ feat_W, const float* __restrict__ feat_b,
    const float* __restrict__ nl1_W, const float* __restrict__ nl1_b,
    const float* __restrict__ nl2_W, const float* __restrict__ nl2_b,
    float* __restrict__ feat_imp)
{
  extern __shared__ char smem_[];
  uint32_t (*WfT)[1024]   = (uint32_t(*)[1024])(smem_);
  uint32_t (*nl1T)[32]    = (uint32_t(*)[32])(smem_ + 65536);
  uint32_t (*xp)[16]      = (uint32_t(*)[16])(smem_ + 67584);
  uint32_t (*hidp)[32][16]= (uint32_t(*)[32][16])(smem_ + 67840);
  const int tid = threadIdx.x;
  const int lane = tid & 31;
  const int ig = tid >> 5;        // 0..15
  const int i0 = ig, i1 = ig + 16;
  for (int idx = tid; idx < 16*1024; idx += 512){
    const int k = idx >> 10, rr = idx & 1023;
    const int i = rr >> 5;
    float a = feat_W[(size_t)rr*32 + 2*k];
    float c2 = feat_W[(size_t)rr*32 + 2*k + 1];
    if (2*k == i) a = 0.f;
    if (2*k+1 == i) c2 = 0.f;
    WfT[k][rr] = pack2u_(a, c2);
  }
  for (int idx = tid; idx < 16*32; idx += 512){
    const int k = idx >> 5, g = idx & 31;
    nl1T[k][g] = pack2u_(nl1_W[g*32 + 2*k], nl1_W[g*32 + 2*k + 1]);
  }
  const float fb0 = feat_b[i0*32 + lane];
  const float fb1 = feat_b[i1*32 + lane];
  const float n1b = nl1_b[lane];
  const float n2w = nl2_W[lane];
  const float n2b = nl2_b[0];
  __syncthreads();
  const int NQ = (NB*NT)/4;
  for (int rq = blockIdx.x; rq < NQ; rq += gridDim.x){
    const int r = rq*4;
    if (tid < 128){
      const int qq = tid >> 5, v = tid & 31;
      const float xv = x_comp[(size_t)(r+qq)*32 + v];
      const float pr = __shfl_xor(xv, 1);
      if (!(v & 1)) xp[qq][v>>1] = pack2u_(xv, pr);
    }
    __syncthreads();
    uint32_t wa[16], wb[16];
    #pragma unroll
    for (int k=0;k<16;k++){ wa[k] = WfT[k][i0*32+lane]; wb[k] = WfT[k][i1*32+lane]; }
    float za[4], zb[4];
    #pragma unroll
    for (int qq=0;qq<4;qq++){
      const uint4* xq = (const uint4*)xp[qq];
      const uint4 X0=xq[0], X1=xq[1], X2=xq[2], X3=xq[3];
      float s0 = fb0, s1 = fb1;
      s0=dot2u_(X0.x,wa[0],s0);  s1=dot2u_(X0.x,wb[0],s1);
      s0=dot2u_(X0.y,wa[1],s0);  s1=dot2u_(X0.y,wb[1],s1);
      s0=dot2u_(X0.z,wa[2],s0);  s1=dot2u_(X0.z,wb[2],s1);
      s0=dot2u_(X0.w,wa[3],s0);  s1=dot2u_(X0.w,wb[3],s1);
      s0=dot2u_(X1.x,wa[4],s0);  s1=dot2u_(X1.x,wb[4],s1);
      s0=dot2u_(X1.y,wa[5],s0);  s1=dot2u_(X1.y,wb[5],s1);
      s0=dot2u_(X1.z,wa[6],s0);  s1=dot2u_(X1.z,wb[6],s1);
      s0=dot2u_(X1.w,wa[7],s0);  s1=dot2u_(X1.w,wb[7],s1);
      s0=dot2u_(X2.x,wa[8],s0);  s1=dot2u_(X2.x,wb[8],s1);
      s0=dot2u_(X2.y,wa[9],s0);  s1=dot2u_(X2.y,wb[9],s1);
      s0=dot2u_(X2.z,wa[10],s0); s1=dot2u_(X2.z,wb[10],s1);
      s0=dot2u_(X2.w,wa[11],s0); s1=dot2u_(X2.w,wb[11],s1);
      s0=dot2u_(X3.x,wa[12],s0); s1=dot2u_(X3.x,wb[12],s1);
      s0=dot2u_(X3.y,wa[13],s0); s1=dot2u_(X3.y,wb[13],s1);
      s0=dot2u_(X3.z,wa[14],s0); s1=dot2u_(X3.z,wb[14],s1);
      s0=dot2u_(X3.w,wa[15],s0); s1=dot2u_(X3.w,wb[15],s1);
      za[qq] = fmaxf(s0, 0.f); zb[qq] = fmaxf(s1, 0.f);
    }
    #pragma unroll
    for (int qq=0;qq<4;qq++){
      const float pa = __shfl_xor(za[qq], 1);
      const float pb = __shfl_xor(zb[qq], 1);
      if (!(lane & 1)){
        hidp[qq][i0][lane>>1] = pack2u_(za[qq], pa);
        hidp[qq][i1][lane>>1] = pack2u_(zb[qq], pb);
      }
    }
    __syncthreads();
    uint32_t nw[16];
    #pragma unroll
    for (int k=0;k<16;k++) nw[k] = nl1T[k][lane];
    float o[8];
    #pragma unroll
    for (int qq=0;qq<4;qq++){
      const uint4* h0p = (const uint4*)hidp[qq][i0];
      const uint4* h1p = (const uint4*)hidp[qq][i1];
      float s0 = n1b, s1 = n1b;
      #pragma unroll
      for (int c4=0;c4<4;c4++){
        const uint4 H0 = h0p[c4];
        const uint4 H1 = h1p[c4];
        s0=dot2u_(H0.x,nw[4*c4],s0);   s1=dot2u_(H1.x,nw[4*c4],s1);
        s0=dot2u_(H0.y,nw[4*c4+1],s0); s1=dot2u_(H1.y,nw[4*c4+1],s1);
        s0=dot2u_(H0.z,nw[4*c4+2],s0); s1=dot2u_(H1.z,nw[4*c4+2],s1);
        s0=dot2u_(H0.w,nw[4*c4+3],s0); s1=dot2u_(H1.w,nw[4*c4+3],s1);
      }
      o[2*qq]   = fmaxf(s0,0.f)*n2w;
      o[2*qq+1] = fmaxf(s1,0.f)*n2w;
    }
    #pragma unroll
    for (int m=0;m<8;m++){
      #pragma unroll
      for (int off=16; off>0; off>>=1) o[m] += __shfl_xor(o[m], off, 32);
    }
    if (lane == 0){
      #pragma unroll
      for (int qq=0;qq<4;qq++){
        feat_imp[(size_t)(r+qq)*32 + i0] = o[2*qq]   + n2b;
        feat_imp[(size_t)(r+qq)*32 + i1] = o[2*qq+1] + n2b;
      }
    }
    __syncthreads();
  }
}

// ---------------- rnn_imp GEMM + fuse + final: LDS f16 rimp ----------------
__global__ __launch_bounds__(512) void k_final(
    const float* __restrict__ values, const float* __restrict__ masks,
    const float* __restrict__ feat_imp, const float* __restrict__ hidden,
    const float* __restrict__ rimp_W, const float* __restrict__ rimp_b,
    const float* __restrict__ fuse_W, const float* __restrict__ fuse_b,
    const int* __restrict__ lengths, float* __restrict__ out)
{
  const int tid = threadIdx.x;
  const int v = tid & 31;
  const int grp = (tid >> 5) & 7;
  const int half = tid >> 8;
  __shared__ uint32_t rpT[64][32];
  __shared__ __align__(16) uint32_t hrowp[8][64];
  __shared__ float rpart[8][32];
  __shared__ float bpart[8][32];
  for (int idx = tid; idx < 64*32; idx += 512){
    const int k = idx >> 5, vv = idx & 31;
    rpT[k][vv] = pack2u_(rimp_W[(size_t)vv*128 + 2*k], rimp_W[(size_t)vv*128 + 2*k+1]);
  }
  const float4* F4 = (const float4*)(fuse_W + (size_t)v*64 + 32);
  float fconst = 0.f;
  if (!half){
    fconst = fuse_b[v];
    #pragma unroll
    for (int q=0;q<8;q++){
      const float4 fw = *(const float4*)(fuse_W + (size_t)v*64 + 4*q);
      fconst += (fw.x+fw.y)+(fw.z+fw.w);
    }
  }
  const float rbias = rimp_b[v];
  __syncthreads();
  const int NOCT = (NB*NT)/8;
  for (int oc = blockIdx.x; oc < NOCT; oc += gridDim.x){
    const size_t base = (size_t)oc*8;
    __syncthreads();
    if (tid < 256){
      const float4 hv = ((const float4*)(hidden + base*128))[tid];
      const int row = tid >> 5;
      const int w0 = (tid & 31) << 1;
      hrowp[row][w0]   = pack2u_(hv.x, hv.y);
      hrowp[row][w0+1] = pack2u_(hv.z, hv.w);
    }
    __syncthreads();
    const size_t r = base + grp;
    float a = half ? 0.f : rbias;
    {
      const uint4* hp4 = (const uint4*)&hrowp[grp][half*32];
      #pragma unroll
      for (int c4=0;c4<8;c4++){
        const uint4 H = hp4[c4];
        a = dot2u_(H.x, rpT[half*32 + 4*c4][v],     a);
        a = dot2u_(H.y, rpT[half*32 + 4*c4 + 1][v], a);
        a = dot2u_(H.z, rpT[half*32 + 4*c4 + 2][v], a);
        a = dot2u_(H.w, rpT[half*32 + 4*c4 + 3][v], a);
      }
    }
    if (half){
      rpart[grp][v] = a;
      const float* mrow = masks + r*32;
      float m0=0,m1=0,m2=0,m3=0;
      #pragma unroll
      for (int q=0;q<8;q++){
        const float4 mv = *(const float4*)(mrow + 4*q);
        const float4 fv = F4[q];
        m0 = fmaf(mv.x, fv.x, m0); m1 = fmaf(mv.y, fv.y, m1);
        m2 = fmaf(mv.z, fv.z, m2); m3 = fmaf(mv.w, fv.w, m3);
      }
      bpart[grp][v] = (m0+m1)+(m2+m3);
    }
    __syncthreads();
    if (!half){
      const int bb = (int)(r >> 9);
      const int t  = (int)(r & 511);
      const int len = lengths[bb];
      const float rimp = a + rpart[grp][v];
      const float beta = sigmoidf_(fconst + bpart[grp][v]);
      const float fi = feat_imp[r*32+v];
      const float m  = masks[r*32+v];
      const float val= values[r*32+v];
      const float fz = beta*fi + (1.0f-beta)*rimp;
      const float o = m*val + (1.0f-m)*fz;
      out[r*32+v] = (t < len) ? o : 0.0f;
    }
  }
}

extern "C" void kernel_launch(void* const* d_in, const int* in_sizes, int n_in,
                              void* d_out, int out_size, void* d_ws, size_t ws_size,
                              hipStream_t stream) {
  const float* values   = (const float*)d_in[0];
  const float* masks    = (const float*)d_in[1];
  const float* rain_f   = (const float*)d_in[2];
  const float* rain_b   = (const float*)d_in[3];
  const float* cmlp_W1  = (const float*)d_in[4];
  const float* cmlp_b1  = (const float*)d_in[5];
  const float* cmlp_W2  = (const float*)d_in[6];
  const float* cmlp_b2  = (const float*)d_in[7];
  const float* gru_Wih  = (const float*)d_in[8];
  const float* gru_Whh  = (const float*)d_in[9];
  const float* gru_bih  = (const float*)d_in[10];
  const float* gru_bhh  = (const float*)d_in[11];
  const float* init_W   = (const float*)d_in[12];
  const float* init_b   = (const float*)d_in[13];
  const float* lstmf_Wih= (const float*)d_in[14];
  const float* lstmf_Whh= (const float*)d_in[15];
  const float* lstmf_bih= (const float*)d_in[16];
  const float* lstmf_bhh= (const float*)d_in[17];
  const float* lstmb_Wih= (const float*)d_in[18];
  const float* lstmb_Whh= (const float*)d_in[19];
  const float* lstmb_bih= (const float*)d_in[20];
  const float* lstmb_bhh= (const float*)d_in[21];
  const float* rimp_W   = (const float*)d_in[22];
  const float* rimp_b   = (const float*)d_in[23];
  const float* feat_W   = (const float*)d_in[24];
  const float* feat_b   = (const float*)d_in[25];
  const float* nl1_W    = (const float*)d_in[26];
  const float* nl1_b    = (const float*)d_in[27];
  const float* nl2_W    = (const float*)d_in[28];
  const float* nl2_b    = (const float*)d_in[29];
  const float* fuse_W   = (const float*)d_in[30];
  const float* fuse_b   = (const float*)d_in[31];
  const int*   lengths  = (const int*)d_in[32];
  float* out = (float*)d_out;

  float* ws       = (float*)d_ws;
  float* x_comp   = ws;                                   // B*T*V
  float* stats    = x_comp + (size_t)NB*NT*NV;            // B*97
  float* ctx      = stats + NB*97;                        // B*64
  float* h0       = ctx + NB*64;                          // B*128
  float* c0      = h0 + NB*128;                           // B*128
  float* cgF      = c0 + NB*128;                          // B*256
  float* cgB      = cgF + NB*256;                         // B*256
  float* hidden   = cgB + NB*256;                         // B*T*128
  float* feat_imp = hidden + (size_t)NB*NT*128;           // B*T*V
  unsigned short* gig = (unsigned short*)(feat_imp + (size_t)NB*NT*NV); // B*T*96 f16
  // total ~127 MB

  k_stats<<<NB, 256, 0, stream>>>(values, masks, lengths, x_comp, stats);
  k_gigru<<<1024, 128, 0, stream>>>(x_comp, rain_f, rain_b, gru_Wih, gru_bih, gig);
  k_cmlp<<<NB, 64, 0, stream>>>(stats, cmlp_W1, cmlp_b1, cmlp_W2, cmlp_b2, ctx);
  k_gru<<<NB, 128, 0, stream>>>(gig, lengths, gru_Whh, gru_bhh, ctx);
  k_init<<<NB, 256, 0, stream>>>(ctx, init_W, init_b,
                                 lstmf_Wih, lstmf_bih, lstmf_bhh,
                                 lstmb_Wih, lstmb_bih, lstmb_bhh,
                                 h0, c0, cgF, cgB, hidden);
  dim3 lgrid(NB/2, 2);
  k_lstm<<<lgrid, 512, 78592, stream>>>(x_comp, masks,
                                        lstmf_Wih, lstmf_Whh, lstmb_Wih, lstmb_Whh,
                                        cgF, cgB, h0, c0, lengths, hidden);
  k_feat<<<512, 512, 76032, stream>>>(x_comp, feat_W, feat_b, nl1_W, nl1_b, nl2_W, nl2_b, feat_imp);
  k_final<<<2048, 512, 0, stream>>>(values, masks, feat_imp, hidden,
                                    rimp_W, rimp_b, fuse_W, fuse_b, lengths, out);
}

// Round 12
// 1459.783 us; speedup vs baseline: 1.8031x; 1.0968x over previous
//
#include <hip/hip_runtime.h>
#include <cstddef>
#include <cstdint>

constexpr int NB = 256;
constexpr int NT = 512;
constexpr int NV = 32;

typedef _Float16 h2_t __attribute__((ext_vector_type(2)));
typedef _Float16 f16x8 __attribute__((ext_vector_type(8)));
typedef float f32x4 __attribute__((ext_vector_type(4)));

__device__ __forceinline__ float sigmoidf_(float x){ return 1.0f/(1.0f+__expf(-x)); }
__device__ __forceinline__ float tanhf_(float x){ return 1.0f - 2.0f/(__expf(2.0f*x)+1.0f); }

__device__ __forceinline__ uint32_t pack2u_(float a, float b){
  h2_t r; r.x=(_Float16)a; r.y=(_Float16)b; return __builtin_bit_cast(uint32_t, r);
}
__device__ __forceinline__ float dot2u_(uint32_t u, uint32_t w, float c){
#if __has_builtin(__builtin_amdgcn_fdot2)
  return __builtin_amdgcn_fdot2(__builtin_bit_cast(h2_t,u), __builtin_bit_cast(h2_t,w), c, false);
#else
  h2_t a=__builtin_bit_cast(h2_t,u), b=__builtin_bit_cast(h2_t,w);
  return c + (float)a.x*(float)b.x + (float)a.y*(float)b.y;
#endif
}
__device__ __forceinline__ float h2f_(unsigned short u){
  _Float16 hv = __builtin_bit_cast(_Float16, u); return (float)hv;
}
__device__ __forceinline__ unsigned short f2h_(float a){
  _Float16 hv = (_Float16)a; return __builtin_bit_cast(unsigned short, hv);
}

#define Q4(acc, Wv, Uv) { acc=dot2u_((Uv).x,(Wv).x,acc); acc=dot2u_((Uv).y,(Wv).y,acc); \
                          acc=dot2u_((Uv).z,(Wv).z,acc); acc=dot2u_((Uv).w,(Wv).w,acc); }

// ---------------- stats + x_comp ----------------
__global__ __launch_bounds__(256) void k_stats(
    const float* __restrict__ values, const float* __restrict__ masks,
    const int* __restrict__ lengths,
    float* __restrict__ x_comp, float* __restrict__ stats)
{
  const int b = blockIdx.x;
  const int v = threadIdx.x & 31;
  const int g = threadIdx.x >> 5;
  const int len = lengths[b];
  const float* vb = values + (size_t)b*NT*NV;
  const float* mb = masks  + (size_t)b*NT*NV;
  float* xb = x_comp + (size_t)b*NT*NV;
  float s_m=0.f, s_mv=0.f, s_v=0.f, s_v2=0.f;
  for (int t=g; t<NT; t+=8){
    float val = vb[t*NV+v];
    float m   = mb[t*NV+v];
    float xp  = (t==0) ? vb[v] : vb[(t-1)*NV+v];
    float pm  = (t<len) ? 1.0f : 0.0f;
    xb[t*NV+v] = (m*val + (1.0f-m)*xp)*pm;
    s_m += m; s_mv += m*val; s_v += val; s_v2 += val*val;
  }
  __shared__ float red[4][8][32];
  red[0][g][v]=s_m; red[1][g][v]=s_mv; red[2][g][v]=s_v; red[3][g][v]=s_v2;
  __syncthreads();
  if (g==0){
    float a0=0,a1=0,a2=0,a3=0;
    #pragma unroll
    for(int i=0;i<8;i++){ a0+=red[0][i][v]; a1+=red[1][i][v]; a2+=red[2][i][v]; a3+=red[3][i][v]; }
    float msum = fmaxf(a0, 1.0f);
    float mean = a1/msum;
    float dss  = a3 - 2.0f*mean*a2 + (float)NT*mean*mean;
    float var  = (msum > 1.0f) ? dss/(msum-1.0f) : 0.0f;
    float sd   = sqrtf(fmaxf(var, 0.0f));
    float miss = 1.0f - a0 / fmaxf((float)len, 1.0f);
    float* st = stats + b*97;
    if (v==0) st[0] = (float)len;
    st[1+v]=mean; st[33+v]=sd; st[65+v]=miss;
  }
}

// ---------------- context MLP ----------------
__global__ __launch_bounds__(64) void k_cmlp(
    const float* __restrict__ stats,
    const float* __restrict__ W1, const float* __restrict__ b1,
    const float* __restrict__ W2, const float* __restrict__ b2,
    float* __restrict__ ctx)
{
  const int b = blockIdx.x;
  const int j = threadIdx.x;
  __shared__ float st[97];
  __shared__ float hm[64];
  for (int k=j; k<97; k+=64) st[k] = stats[b*97+k];
  __syncthreads();
  float a0=b1[j], a1=0.f, a2=0.f, a3=0.f;
  #pragma unroll
  for (int k=0; k<96; k+=4){
    a0 += st[k]*W1[j*97+k];     a1 += st[k+1]*W1[j*97+k+1];
    a2 += st[k+2]*W1[j*97+k+2]; a3 += st[k+3]*W1[j*97+k+3];
  }
  a0 += st[96]*W1[j*97+96];
  hm[j] = fmaxf((a0+a1)+(a2+a3), 0.0f);
  __syncthreads();
  if (j < 32){
    float c0_=b2[j], c1=0.f, c2=0.f, c3=0.f;
    #pragma unroll
    for (int k=0;k<64;k+=4){
      c0_ += hm[k]*W2[j*64+k];    c1 += hm[k+1]*W2[j*64+k+1];
      c2 += hm[k+2]*W2[j*64+k+2]; c3 += hm[k+3]*W2[j*64+k+3];
    }
    ctx[b*64+j] = (c0_+c1)+(c2+c3);
  }
}

// ---------------- GRU x-part GEMM: gig[b*T][96] f16 ----------------
__global__ __launch_bounds__(128) void k_gigru(
    const float* __restrict__ x_comp, const float* __restrict__ rain_f,
    const float* __restrict__ rain_b,
    const float* __restrict__ Wih, const float* __restrict__ bih,
    unsigned short* __restrict__ gig)
{
  __shared__ uint32_t WT[48][98];
  __shared__ __align__(16) uint32_t us[8][48];
  const int tid = threadIdx.x;
  for (int idx = tid; idx < 48*96; idx += 128){
    const int k = idx / 96, col = idx - k*96;
    WT[k][col] = pack2u_(Wih[(size_t)col*96 + 2*k], Wih[(size_t)col*96 + 2*k + 1]);
  }
  const float bias = (tid < 96) ? bih[tid] : 0.f;
  __syncthreads();
  const int NR = NB*NT;
  for (int r0 = blockIdx.x*8; r0 < NR; r0 += gridDim.x*8){
    __syncthreads();
    for (int idx = tid; idx < 8*48; idx += 128){
      const int r = idx / 48, w = idx - r*48;
      const size_t row = (size_t)r0 + r;
      const int i0 = 2*w, i1 = 2*w+1;
      const float a = (i0<32)? x_comp[row*32+i0] : (i0<64 ? rain_f[row*32+i0-32] : rain_b[row*32+i0-64]);
      const float c = (i1<32)? x_comp[row*32+i1] : (i1<64 ? rain_f[row*32+i1-32] : rain_b[row*32+i1-64]);
      us[r][w] = pack2u_(a, c);
    }
    __syncthreads();
    if (tid < 96){
      #pragma unroll
      for (int r=0;r<8;r++){
        const uint4* U = (const uint4*)us[r];
        float acc = bias;
        #pragma unroll
        for (int k4=0;k4<12;k4++){
          const uint4 u4 = U[k4];
          acc = dot2u_(u4.x, WT[4*k4][tid],   acc);
          acc = dot2u_(u4.y, WT[4*k4+1][tid], acc);
          acc = dot2u_(u4.z, WT[4*k4+2][tid], acc);
          acc = dot2u_(u4.w, WT[4*k4+3][tid], acc);
        }
        gig[((size_t)r0+r)*96 + tid] = f2h_(acc);
      }
    }
  }
}

// ---------------- GRU scan: 1 chain/block, grid 256, weights in LDS ----------------
__global__ __launch_bounds__(128) void k_gru(
    const unsigned short* __restrict__ gig, const int* __restrict__ lengths,
    const float* __restrict__ Whh, const float* __restrict__ bhh,
    float* __restrict__ ctx)
{
  __shared__ uint32_t Wg[96*20];
  __shared__ __align__(16) uint32_t hp[16];
  __shared__ float gpart[96];
  const int b = blockIdx.x;
  const int tid = threadIdx.x;
  for (int idx = tid; idx < 96*16; idx += 128){
    const int row = idx >> 4, k = idx & 15;
    Wg[row*20+k] = pack2u_(Whh[row*32+2*k], Whh[row*32+2*k+1]);
  }
  const float bh = (tid < 96) ? bhh[tid] : 0.f;
  int len = lengths[b]; if (len > NT) len = NT;
  float h = 0.f;
  if (tid < 16) hp[tid] = 0u;
  const unsigned short* gp = gig + (size_t)b*NT*96;
  float gir=0.f, giz=0.f, gin=0.f;
  if (tid < 32 && len > 0){ gir=h2f_(gp[tid]); giz=h2f_(gp[32+tid]); gin=h2f_(gp[64+tid]); }
  __syncthreads();
  for (int t=0; t<len; ++t){
    float nr=0.f, nz=0.f, nn=0.f;
    if (tid < 32 && t+1 < len){
      const unsigned short* gn = gp + (size_t)(t+1)*96;
      nr=h2f_(gn[tid]); nz=h2f_(gn[32+tid]); nn=h2f_(gn[64+tid]);
    }
    if (tid < 96){
      const uint4* W4 = (const uint4*)(Wg + tid*20);
      const uint4 w0=W4[0], w1=W4[1], w2=W4[2], w3=W4[3];
      const uint4* H4 = (const uint4*)hp;
      const uint4 H0=H4[0], H1=H4[1], H2=H4[2], H3=H4[3];
      float acc = bh;
      Q4(acc,w0,H0) Q4(acc,w1,H1) Q4(acc,w2,H2) Q4(acc,w3,H3)
      gpart[tid] = acc;
    }
    __syncthreads();
    if (tid < 32){
      const float r = sigmoidf_(gir + gpart[tid]);
      const float z = sigmoidf_(giz + gpart[32+tid]);
      const float n = tanhf_(gin + r*gpart[64+tid]);
      h = (1.0f - z)*n + z*h;
      gir=nr; giz=nz; gin=nn;
      const float pr = __shfl_xor(h, 1);
      if (!(tid & 1)) hp[tid>>1] = pack2u_(h, pr);
    }
    __syncthreads();
  }
  if (tid < 32) ctx[b*64 + 32 + tid] = h;
}

// ---------------- init: h0/c0, ctx-part of LSTM gates, hidden seeds ----------------
__global__ __launch_bounds__(256) void k_init(
    const float* __restrict__ ctx,
    const float* __restrict__ initW, const float* __restrict__ initb,
    const float* __restrict__ WihF, const float* __restrict__ bihF, const float* __restrict__ bhhF,
    const float* __restrict__ WihB, const float* __restrict__ bihB, const float* __restrict__ bhhB,
    float* __restrict__ h0, float* __restrict__ c0,
    float* __restrict__ cgF, float* __restrict__ cgB,
    float* __restrict__ hidden)
{
  const int b = blockIdx.x;
  const int j = threadIdx.x;
  __shared__ __align__(16) float cv[64];
  if (j < 64) cv[j] = ctx[b*64+j];
  __syncthreads();
  {
    float4 f = {bihF[j]+bhhF[j], 0.f, 0.f, 0.f};
    float4 g = {bihB[j]+bhhB[j], 0.f, 0.f, 0.f};
    #pragma unroll
    for (int q=0;q<16;q++){
      const float4 cvv = *(const float4*)&cv[4*q];
      const float4 wf = *(const float4*)(WihF + (size_t)j*128 + 64 + 4*q);
      const float4 wb = *(const float4*)(WihB + (size_t)j*128 + 64 + 4*q);
      f.x += cvv.x*wf.x; f.y += cvv.y*wf.y; f.z += cvv.z*wf.z; f.w += cvv.w*wf.w;
      g.x += cvv.x*wb.x; g.y += cvv.y*wb.y; g.z += cvv.z*wb.z; g.w += cvv.w*wb.w;
    }
    cgF[b*256+j] = (f.x+f.y)+(f.z+f.w);
    cgB[b*256+j] = (g.x+g.y)+(g.z+g.w);
  }
  if (j < 128){
    float4 a = {initb[j], 0.f, 0.f, 0.f};
    #pragma unroll
    for (int q=0;q<16;q++){
      const float4 cvv = *(const float4*)&cv[4*q];
      const float4 w  = *(const float4*)(initW + (size_t)j*64 + 4*q);
      a.x += cvv.x*w.x; a.y += cvv.y*w.y; a.z += cvv.z*w.z; a.w += cvv.w*w.w;
    }
    float hv = (a.x+a.y)+(a.z+a.w);
    h0[b*128+j] = hv;
    c0[b*128+j] = tanhf_(hv);
    if (j < 64) hidden[(size_t)b*NT*128 + j] = hv;                                // fwd seed t=0
    else        hidden[(size_t)b*NT*128 + (size_t)(NT-1)*128 + 64 + (j-64)] = hv; // bwd seed t=T-1
  }
}

// ---------------- LSTM scan: MFMA, weights resident in register A-fragments ----------------
// block = (b, dir), 512 thr = 8 waves; wave w owns gates [32w, 32w+32) = 2 m-tiles.
// A-frags (Wx 2x2 + Wh 2x2 = 8 frags = 32 VGPR/lane) loaded once; remat forbidden by mem-clobber.
// B-operand u/h broadcast to all 16 MFMA columns -> every column computes the gate vector;
// lanes (l&15)==0 write C (C/D: row=(l>>4)*4+j, col=l&15).
__global__ __launch_bounds__(512,2) void k_lstm(
    const float* __restrict__ x_comp, const float* __restrict__ masks,
    const float* __restrict__ WihF, const float* __restrict__ WhhF,
    const float* __restrict__ WihB, const float* __restrict__ WhhB,
    const float* __restrict__ cgF, const float* __restrict__ cgB,
    const float* __restrict__ h0, const float* __restrict__ c0,
    const int* __restrict__ lengths,
    float* __restrict__ hidden)
{
  __shared__ __align__(16) _Float16 ubuf[2][64];
  __shared__ __align__(16) _Float16 hbuf[64];
  __shared__ __align__(16) float gbuf[256];
  const int b = blockIdx.x, dir = blockIdx.y;
  const int tid = threadIdx.x;
  const int l = tid & 63, wv = tid >> 6;
  const int m0 = wv * 32;
  const int arow = l & 15, ak = (l >> 4) * 8;
  const float* Wih = dir ? WihB : WihF;
  const float* Whh = dir ? WhhB : WhhF;
  f16x8 AX00, AX01, AX10, AX11, AH00, AH01, AH10, AH11;
  #define LDFRAG(dst, base, ld, row, kk) { \
    const float* p_ = (base) + (size_t)(row)*(ld) + (kk); \
    const float4 v0_ = *(const float4*)p_; const float4 v1_ = *(const float4*)(p_+4); \
    f16x8 t_; t_[0]=(_Float16)v0_.x; t_[1]=(_Float16)v0_.y; t_[2]=(_Float16)v0_.z; t_[3]=(_Float16)v0_.w; \
    t_[4]=(_Float16)v1_.x; t_[5]=(_Float16)v1_.y; t_[6]=(_Float16)v1_.z; t_[7]=(_Float16)v1_.w; dst = t_; }
  LDFRAG(AX00, Wih, 128, m0+arow,    ak)
  LDFRAG(AX01, Wih, 128, m0+arow,    32+ak)
  LDFRAG(AX10, Wih, 128, m0+16+arow, ak)
  LDFRAG(AX11, Wih, 128, m0+16+arow, 32+ak)
  LDFRAG(AH00, Whh, 64,  m0+arow,    ak)
  LDFRAG(AH01, Whh, 64,  m0+arow,    32+ak)
  LDFRAG(AH10, Whh, 64,  m0+16+arow, ak)
  LDFRAG(AH11, Whh, 64,  m0+16+arow, 32+ak)
  #undef LDFRAG
  const float* cgp = (dir ? cgB : cgF) + (size_t)b*256;
  const int crow = (l >> 4) * 4;
  const f32x4 cg0 = *(const f32x4*)(cgp + m0 + crow);
  const f32x4 cg1 = *(const f32x4*)(cgp + m0 + 16 + crow);
  asm volatile("" ::: "memory");   // loads above cannot be rematerialized past this
  const int len = lengths[b];
  int nsteps = NT-1;
  if (dir == 0){ int e = len-1; if (e<0) e=0; if (e<nsteps) nsteps = e; }
  const float* xc = x_comp + (size_t)b*NT*NV;
  const float* mk = masks  + (size_t)b*NT*NV;
  float* hout = hidden + (size_t)b*NT*128 + dir*64;
  float cst = 0.f;
  if (tid < 64){
    const float hv = h0[(size_t)b*128 + dir*64 + tid];
    cst            = c0[(size_t)b*128 + dir*64 + tid];
    hbuf[tid] = (_Float16)hv;
  }
  if (tid >= 64 && tid < 96 && nsteps > 0){
    const int u = tid - 64;
    const int t0 = dir ? NT-1 : 0;
    const float2 v = (u<16) ? *(const float2*)(xc + t0*NV + 2*u)
                            : *(const float2*)(mk + t0*NV + 2*(u-16));
    ubuf[0][2*u] = (_Float16)v.x; ubuf[0][2*u+1] = (_Float16)v.y;
  }
  __syncthreads();
  for (int s=0; s<nsteps; ++s){
    const int cur = s & 1;
    float2 pre = {0.f, 0.f};
    const bool dopf = (tid >= 64 && tid < 96 && s+1 < nsteps);
    if (dopf){
      const int u = tid - 64;
      const int tn = dir ? (NT-2-s) : (s+1);
      pre = (u<16) ? *(const float2*)(xc + tn*NV + 2*u)
                   : *(const float2*)(mk + tn*NV + 2*(u-16));
    }
    const f16x8 bu0 = *(const f16x8*)&ubuf[cur][ak];
    const f16x8 bu1 = *(const f16x8*)&ubuf[cur][32+ak];
    const f16x8 bh0 = *(const f16x8*)&hbuf[ak];
    const f16x8 bh1 = *(const f16x8*)&hbuf[32+ak];
    f32x4 a0 = cg0, a1 = cg1;
    a0 = __builtin_amdgcn_mfma_f32_16x16x32_f16(AX00, bu0, a0, 0, 0, 0);
    a0 = __builtin_amdgcn_mfma_f32_16x16x32_f16(AX01, bu1, a0, 0, 0, 0);
    a0 = __builtin_amdgcn_mfma_f32_16x16x32_f16(AH00, bh0, a0, 0, 0, 0);
    a0 = __builtin_amdgcn_mfma_f32_16x16x32_f16(AH01, bh1, a0, 0, 0, 0);
    a1 = __builtin_amdgcn_mfma_f32_16x16x32_f16(AX10, bu0, a1, 0, 0, 0);
    a1 = __builtin_amdgcn_mfma_f32_16x16x32_f16(AX11, bu1, a1, 0, 0, 0);
    a1 = __builtin_amdgcn_mfma_f32_16x16x32_f16(AH10, bh0, a1, 0, 0, 0);
    a1 = __builtin_amdgcn_mfma_f32_16x16x32_f16(AH11, bh1, a1, 0, 0, 0);
    if ((l & 15) == 0){
      *(f32x4*)&gbuf[m0 + crow]      = a0;
      *(f32x4*)&gbuf[m0 + 16 + crow] = a1;
    }
    if (dopf){
      const int u = tid - 64;
      ubuf[cur^1][2*u]   = (_Float16)pre.x;
      ubuf[cur^1][2*u+1] = (_Float16)pre.y;
    }
    __syncthreads();
    if (tid < 64){
      const float gi = gbuf[tid], gf = gbuf[64+tid], gg = gbuf[128+tid], go = gbuf[192+tid];
      cst = sigmoidf_(gf)*cst + sigmoidf_(gi)*tanhf_(gg);
      const float hh = sigmoidf_(go)*tanhf_(cst);
      const int outt = dir ? (NT-2-s) : (s+1);
      hout[(size_t)outt*128 + tid] = hh;
      hbuf[tid] = (_Float16)hh;
    }
    __syncthreads();
  }
}

// ---------------- feature-regression: LDS f16 weights, 4 rows/iter ----------------
__global__ __launch_bounds__(512) void k_feat(
    const float* __restrict__ x_comp,
    const float* __restrict__ feat_W, const float* __restrict__ feat_b,
    const float* __restrict__ nl1_W, const float* __restrict__ nl1_b,
    const float* __restrict__ nl2_W, const float* __restrict__ nl2_b,
    float* __restrict__ feat_imp)
{
  extern __shared__ char smem_[];
  uint32_t (*WfT)[1024]   = (uint32_t(*)[1024])(smem_);
  uint32_t (*nl1T)[32]    = (uint32_t(*)[32])(smem_ + 65536);
  uint32_t (*xp)[16]      = (uint32_t(*)[16])(smem_ + 67584);
  uint32_t (*hidp)[32][16]= (uint32_t(*)[32][16])(smem_ + 67840);
  const int tid = threadIdx.x;
  const int lane = tid & 31;
  const int ig = tid >> 5;        // 0..15
  const int i0 = ig, i1 = ig + 16;
  for (int idx = tid; idx < 16*1024; idx += 512){
    const int k = idx >> 10, rr = idx & 1023;
    const int i = rr >> 5;
    float a = feat_W[(size_t)rr*32 + 2*k];
    float c2 = feat_W[(size_t)rr*32 + 2*k + 1];
    if (2*k == i) a = 0.f;
    if (2*k+1 == i) c2 = 0.f;
    WfT[k][rr] = pack2u_(a, c2);
  }
  for (int idx = tid; idx < 16*32; idx += 512){
    const int k = idx >> 5, g = idx & 31;
    nl1T[k][g] = pack2u_(nl1_W[g*32 + 2*k], nl1_W[g*32 + 2*k + 1]);
  }
  const float fb0 = feat_b[i0*32 + lane];
  const float fb1 = feat_b[i1*32 + lane];
  const float n1b = nl1_b[lane];
  const float n2w = nl2_W[lane];
  const float n2b = nl2_b[0];
  __syncthreads();
  const int NQ = (NB*NT)/4;
  for (int rq = blockIdx.x; rq < NQ; rq += gridDim.x){
    const int r = rq*4;
    if (tid < 128){
      const int qq = tid >> 5, v = tid & 31;
      const float xv = x_comp[(size_t)(r+qq)*32 + v];
      const float pr = __shfl_xor(xv, 1);
      if (!(v & 1)) xp[qq][v>>1] = pack2u_(xv, pr);
    }
    __syncthreads();
    uint32_t wa[16], wb[16];
    #pragma unroll
    for (int k=0;k<16;k++){ wa[k] = WfT[k][i0*32+lane]; wb[k] = WfT[k][i1*32+lane]; }
    float za[4], zb[4];
    #pragma unroll
    for (int qq=0;qq<4;qq++){
      const uint4* xq = (const uint4*)xp[qq];
      const uint4 X0=xq[0], X1=xq[1], X2=xq[2], X3=xq[3];
      float s0 = fb0, s1 = fb1;
      s0=dot2u_(X0.x,wa[0],s0);  s1=dot2u_(X0.x,wb[0],s1);
      s0=dot2u_(X0.y,wa[1],s0);  s1=dot2u_(X0.y,wb[1],s1);
      s0=dot2u_(X0.z,wa[2],s0);  s1=dot2u_(X0.z,wb[2],s1);
      s0=dot2u_(X0.w,wa[3],s0);  s1=dot2u_(X0.w,wb[3],s1);
      s0=dot2u_(X1.x,wa[4],s0);  s1=dot2u_(X1.x,wb[4],s1);
      s0=dot2u_(X1.y,wa[5],s0);  s1=dot2u_(X1.y,wb[5],s1);
      s0=dot2u_(X1.z,wa[6],s0);  s1=dot2u_(X1.z,wb[6],s1);
      s0=dot2u_(X1.w,wa[7],s0);  s1=dot2u_(X1.w,wb[7],s1);
      s0=dot2u_(X2.x,wa[8],s0);  s1=dot2u_(X2.x,wb[8],s1);
      s0=dot2u_(X2.y,wa[9],s0);  s1=dot2u_(X2.y,wb[9],s1);
      s0=dot2u_(X2.z,wa[10],s0); s1=dot2u_(X2.z,wb[10],s1);
      s0=dot2u_(X2.w,wa[11],s0); s1=dot2u_(X2.w,wb[11],s1);
      s0=dot2u_(X3.x,wa[12],s0); s1=dot2u_(X3.x,wb[12],s1);
      s0=dot2u_(X3.y,wa[13],s0); s1=dot2u_(X3.y,wb[13],s1);
      s0=dot2u_(X3.z,wa[14],s0); s1=dot2u_(X3.z,wb[14],s1);
      s0=dot2u_(X3.w,wa[15],s0); s1=dot2u_(X3.w,wb[15],s1);
      za[qq] = fmaxf(s0, 0.f); zb[qq] = fmaxf(s1, 0.f);
    }
    #pragma unroll
    for (int qq=0;qq<4;qq++){
      const float pa = __shfl_xor(za[qq], 1);
      const float pb = __shfl_xor(zb[qq], 1);
      if (!(lane & 1)){
        hidp[qq][i0][lane>>1] = pack2u_(za[qq], pa);
        hidp[qq][i1][lane>>1] = pack2u_(zb[qq], pb);
      }
    }
    __syncthreads();
    uint32_t nw[16];
    #pragma unroll
    for (int k=0;k<16;k++) nw[k] = nl1T[k][lane];
    float o[8];
    #pragma unroll
    for (int qq=0;qq<4;qq++){
      const uint4* h0p = (const uint4*)hidp[qq][i0];
      const uint4* h1p = (const uint4*)hidp[qq][i1];
      float s0 = n1b, s1 = n1b;
      #pragma unroll
      for (int c4=0;c4<4;c4++){
        const uint4 H0 = h0p[c4];
        const uint4 H1 = h1p[c4];
        s0=dot2u_(H0.x,nw[4*c4],s0);   s1=dot2u_(H1.x,nw[4*c4],s1);
        s0=dot2u_(H0.y,nw[4*c4+1],s0); s1=dot2u_(H1.y,nw[4*c4+1],s1);
        s0=dot2u_(H0.z,nw[4*c4+2],s0); s1=dot2u_(H1.z,nw[4*c4+2],s1);
        s0=dot2u_(H0.w,nw[4*c4+3],s0); s1=dot2u_(H1.w,nw[4*c4+3],s1);
      }
      o[2*qq]   = fmaxf(s0,0.f)*n2w;
      o[2*qq+1] = fmaxf(s1,0.f)*n2w;
    }
    #pragma unroll
    for (int m=0;m<8;m++){
      #pragma unroll
      for (int off=16; off>0; off>>=1) o[m] += __shfl_xor(o[m], off, 32);
    }
    if (lane == 0){
      #pragma unroll
      for (int qq=0;qq<4;qq++){
        feat_imp[(size_t)(r+qq)*32 + i0] = o[2*qq]   + n2b;
        feat_imp[(size_t)(r+qq)*32 + i1] = o[2*qq+1] + n2b;
      }
    }
    __syncthreads();
  }
}

// ---------------- rnn_imp GEMM + fuse + final: LDS f16 rimp ----------------
__global__ __launch_bounds__(512) void k_final(
    const float* __restrict__ values, const float* __restrict__ masks,
    const float* __restrict__ feat_imp, const float* __restrict__ hidden,
    const float* __restrict__ rimp_W, const float* __restrict__ rimp_b,
    const float* __restrict__ fuse_W, const float* __restrict__ fuse_b,
    const int* __restrict__ lengths, float* __restrict__ out)
{
  const int tid = threadIdx.x;
  const int v = tid & 31;
  const int grp = (tid >> 5) & 7;
  const int half = tid >> 8;
  __shared__ uint32_t rpT[64][32];
  __shared__ __align__(16) uint32_t hrowp[8][64];
  __shared__ float rpart[8][32];
  __shared__ float bpart[8][32];
  for (int idx = tid; idx < 64*32; idx += 512){
    const int k = idx >> 5, vv = idx & 31;
    rpT[k][vv] = pack2u_(rimp_W[(size_t)vv*128 + 2*k], rimp_W[(size_t)vv*128 + 2*k+1]);
  }
  const float4* F4 = (const float4*)(fuse_W + (size_t)v*64 + 32);
  float fconst = 0.f;
  if (!half){
    fconst = fuse_b[v];
    #pragma unroll
    for (int q=0;q<8;q++){
      const float4 fw = *(const float4*)(fuse_W + (size_t)v*64 + 4*q);
      fconst += (fw.x+fw.y)+(fw.z+fw.w);
    }
  }
  const float rbias = rimp_b[v];
  __syncthreads();
  const int NOCT = (NB*NT)/8;
  for (int oc = blockIdx.x; oc < NOCT; oc += gridDim.x){
    const size_t base = (size_t)oc*8;
    __syncthreads();
    if (tid < 256){
      const float4 hv = ((const float4*)(hidden + base*128))[tid];
      const int row = tid >> 5;
      const int w0 = (tid & 31) << 1;
      hrowp[row][w0]   = pack2u_(hv.x, hv.y);
      hrowp[row][w0+1] = pack2u_(hv.z, hv.w);
    }
    __syncthreads();
    const size_t r = base + grp;
    float a = half ? 0.f : rbias;
    {
      const uint4* hp4 = (const uint4*)&hrowp[grp][half*32];
      #pragma unroll
      for (int c4=0;c4<8;c4++){
        const uint4 H = hp4[c4];
        a = dot2u_(H.x, rpT[half*32 + 4*c4][v],     a);
        a = dot2u_(H.y, rpT[half*32 + 4*c4 + 1][v], a);
        a = dot2u_(H.z, rpT[half*32 + 4*c4 + 2][v], a);
        a = dot2u_(H.w, rpT[half*32 + 4*c4 + 3][v], a);
      }
    }
    if (half){
      rpart[grp][v] = a;
      const float* mrow = masks + r*32;
      float m0=0,m1=0,m2=0,m3=0;
      #pragma unroll
      for (int q=0;q<8;q++){
        const float4 mv = *(const float4*)(mrow + 4*q);
        const float4 fv = F4[q];
        m0 = fmaf(mv.x, fv.x, m0); m1 = fmaf(mv.y, fv.y, m1);
        m2 = fmaf(mv.z, fv.z, m2); m3 = fmaf(mv.w, fv.w, m3);
      }
      bpart[grp][v] = (m0+m1)+(m2+m3);
    }
    __syncthreads();
    if (!half){
      const int bb = (int)(r >> 9);
      const int t  = (int)(r & 511);
      const int len = lengths[bb];
      const float rimp = a + rpart[grp][v];
      const float beta = sigmoidf_(fconst + bpart[grp][v]);
      const float fi = feat_imp[r*32+v];
      const float m  = masks[r*32+v];
      const float val= values[r*32+v];
      const float fz = beta*fi + (1.0f-beta)*rimp;
      const float o = m*val + (1.0f-m)*fz;
      out[r*32+v] = (t < len) ? o : 0.0f;
    }
  }
}

extern "C" void kernel_launch(void* const* d_in, const int* in_sizes, int n_in,
                              void* d_out, int out_size, void* d_ws, size_t ws_size,
                              hipStream_t stream) {
  const float* values   = (const float*)d_in[0];
  const float* masks    = (const float*)d_in[1];
  const float* rain_f   = (const float*)d_in[2];
  const float* rain_b   = (const float*)d_in[3];
  const float* cmlp_W1  = (const float*)d_in[4];
  const float* cmlp_b1  = (const float*)d_in[5];
  const float* cmlp_W2  = (const float*)d_in[6];
  const float* cmlp_b2  = (const float*)d_in[7];
  const float* gru_Wih  = (const float*)d_in[8];
  const float* gru_Whh  = (const float*)d_in[9];
  const float* gru_bih  = (const float*)d_in[10];
  const float* gru_bhh  = (const float*)d_in[11];
  const float* init_W   = (const float*)d_in[12];
  const float* init_b   = (const float*)d_in[13];
  const float* lstmf_Wih= (const float*)d_in[14];
  const float* lstmf_Whh= (const float*)d_in[15];
  const float* lstmf_bih= (const float*)d_in[16];
  const float* lstmf_bhh= (const float*)d_in[17];
  const float* lstmb_Wih= (const float*)d_in[18];
  const float* lstmb_Whh= (const float*)d_in[19];
  const float* lstmb_bih= (const float*)d_in[20];
  const float* lstmb_bhh= (const float*)d_in[21];
  const float* rimp_W   = (const float*)d_in[22];
  const float* rimp_b   = (const float*)d_in[23];
  const float* feat_W   = (const float*)d_in[24];
  const float* feat_b   = (const float*)d_in[25];
  const float* nl1_W    = (const float*)d_in[26];
  const float* nl1_b    = (const float*)d_in[27];
  const float* nl2_W    = (const float*)d_in[28];
  const float* nl2_b    = (const float*)d_in[29];
  const float* fuse_W   = (const float*)d_in[30];
  const float* fuse_b   = (const float*)d_in[31];
  const int*   lengths  = (const int*)d_in[32];
  float* out = (float*)d_out;

  float* ws       = (float*)d_ws;
  float* x_comp   = ws;                                   // B*T*V
  float* stats    = x_comp + (size_t)NB*NT*NV;            // B*97
  float* ctx      = stats + NB*97;                        // B*64
  float* h0       = ctx + NB*64;                          // B*128
  float* c0      = h0 + NB*128;                           // B*128
  float* cgF      = c0 + NB*128;                          // B*256
  float* cgB      = cgF + NB*256;                         // B*256
  float* hidden   = cgB + NB*256;                         // B*T*128
  float* feat_imp = hidden + (size_t)NB*NT*128;           // B*T*V
  unsigned short* gig = (unsigned short*)(feat_imp + (size_t)NB*NT*NV); // B*T*96 f16
  // total ~127 MB

  k_stats<<<NB, 256, 0, stream>>>(values, masks, lengths, x_comp, stats);
  k_gigru<<<1024, 128, 0, stream>>>(x_comp, rain_f, rain_b, gru_Wih, gru_bih, gig);
  k_cmlp<<<NB, 64, 0, stream>>>(stats, cmlp_W1, cmlp_b1, cmlp_W2, cmlp_b2, ctx);
  k_gru<<<NB, 128, 0, stream>>>(gig, lengths, gru_Whh, gru_bhh, ctx);
  k_init<<<NB, 256, 0, stream>>>(ctx, init_W, init_b,
                                 lstmf_Wih, lstmf_bih, lstmf_bhh,
                                 lstmb_Wih, lstmb_bih, lstmb_bhh,
                                 h0, c0, cgF, cgB, hidden);
  dim3 lgrid(NB, 2);
  k_lstm<<<lgrid, 512, 0, stream>>>(x_comp, masks,
                                    lstmf_Wih, lstmf_Whh, lstmb_Wih, lstmb_Whh,
                                    cgF, cgB, h0, c0, lengths, hidden);
  k_feat<<<512, 512, 76032, stream>>>(x_comp, feat_W, feat_b, nl1_W, nl1_b, nl2_W, nl2_b, feat_imp);
  k_final<<<2048, 512, 0, stream>>>(values, masks, feat_imp, hidden,
                                    rimp_W, rimp_b, fuse_W, fuse_b, lengths, out);
}

// Round 13
// 1109.866 us; speedup vs baseline: 2.3716x; 1.3153x over previous
//
#include <hip/hip_runtime.h>
#include <cstddef>
#include <cstdint>

constexpr int NB = 256;
constexpr int NT = 512;
constexpr int NV = 32;

typedef _Float16 h2_t __attribute__((ext_vector_type(2)));
typedef _Float16 f16x8 __attribute__((ext_vector_type(8)));
typedef float f32x4 __attribute__((ext_vector_type(4)));

__device__ __forceinline__ float sigmoidf_(float x){ return 1.0f/(1.0f+__expf(-x)); }
__device__ __forceinline__ float tanhf_(float x){ return 1.0f - 2.0f/(__expf(2.0f*x)+1.0f); }

__device__ __forceinline__ uint32_t pack2u_(float a, float b){
  h2_t r; r.x=(_Float16)a; r.y=(_Float16)b; return __builtin_bit_cast(uint32_t, r);
}
__device__ __forceinline__ float dot2u_(uint32_t u, uint32_t w, float c){
#if __has_builtin(__builtin_amdgcn_fdot2)
  return __builtin_amdgcn_fdot2(__builtin_bit_cast(h2_t,u), __builtin_bit_cast(h2_t,w), c, false);
#else
  h2_t a=__builtin_bit_cast(h2_t,u), b=__builtin_bit_cast(h2_t,w);
  return c + (float)a.x*(float)b.x + (float)a.y*(float)b.y;
#endif
}
__device__ __forceinline__ float h2f_(unsigned short u){
  _Float16 hv = __builtin_bit_cast(_Float16, u); return (float)hv;
}
__device__ __forceinline__ unsigned short f2h_(float a){
  _Float16 hv = (_Float16)a; return __builtin_bit_cast(unsigned short, hv);
}

#define Q4(acc, Wv, Uv) { acc=dot2u_((Uv).x,(Wv).x,acc); acc=dot2u_((Uv).y,(Wv).y,acc); \
                          acc=dot2u_((Uv).z,(Wv).z,acc); acc=dot2u_((Uv).w,(Wv).w,acc); }

// ---------------- stats + x_comp ----------------
__global__ __launch_bounds__(256) void k_stats(
    const float* __restrict__ values, const float* __restrict__ masks,
    const int* __restrict__ lengths,
    float* __restrict__ x_comp, float* __restrict__ stats)
{
  const int b = blockIdx.x;
  const int v = threadIdx.x & 31;
  const int g = threadIdx.x >> 5;
  const int len = lengths[b];
  const float* vb = values + (size_t)b*NT*NV;
  const float* mb = masks  + (size_t)b*NT*NV;
  float* xb = x_comp + (size_t)b*NT*NV;
  float s_m=0.f, s_mv=0.f, s_v=0.f, s_v2=0.f;
  for (int t=g; t<NT; t+=8){
    float val = vb[t*NV+v];
    float m   = mb[t*NV+v];
    float xp  = (t==0) ? vb[v] : vb[(t-1)*NV+v];
    float pm  = (t<len) ? 1.0f : 0.0f;
    xb[t*NV+v] = (m*val + (1.0f-m)*xp)*pm;
    s_m += m; s_mv += m*val; s_v += val; s_v2 += val*val;
  }
  __shared__ float red[4][8][32];
  red[0][g][v]=s_m; red[1][g][v]=s_mv; red[2][g][v]=s_v; red[3][g][v]=s_v2;
  __syncthreads();
  if (g==0){
    float a0=0,a1=0,a2=0,a3=0;
    #pragma unroll
    for(int i=0;i<8;i++){ a0+=red[0][i][v]; a1+=red[1][i][v]; a2+=red[2][i][v]; a3+=red[3][i][v]; }
    float msum = fmaxf(a0, 1.0f);
    float mean = a1/msum;
    float dss  = a3 - 2.0f*mean*a2 + (float)NT*mean*mean;
    float var  = (msum > 1.0f) ? dss/(msum-1.0f) : 0.0f;
    float sd   = sqrtf(fmaxf(var, 0.0f));
    float miss = 1.0f - a0 / fmaxf((float)len, 1.0f);
    float* st = stats + b*97;
    if (v==0) st[0] = (float)len;
    st[1+v]=mean; st[33+v]=sd; st[65+v]=miss;
  }
}

// ---------------- context MLP ----------------
__global__ __launch_bounds__(64) void k_cmlp(
    const float* __restrict__ stats,
    const float* __restrict__ W1, const float* __restrict__ b1,
    const float* __restrict__ W2, const float* __restrict__ b2,
    float* __restrict__ ctx)
{
  const int b = blockIdx.x;
  const int j = threadIdx.x;
  __shared__ float st[97];
  __shared__ float hm[64];
  for (int k=j; k<97; k+=64) st[k] = stats[b*97+k];
  __syncthreads();
  float a0=b1[j], a1=0.f, a2=0.f, a3=0.f;
  #pragma unroll
  for (int k=0; k<96; k+=4){
    a0 += st[k]*W1[j*97+k];     a1 += st[k+1]*W1[j*97+k+1];
    a2 += st[k+2]*W1[j*97+k+2]; a3 += st[k+3]*W1[j*97+k+3];
  }
  a0 += st[96]*W1[j*97+96];
  hm[j] = fmaxf((a0+a1)+(a2+a3), 0.0f);
  __syncthreads();
  if (j < 32){
    float c0_=b2[j], c1=0.f, c2=0.f, c3=0.f;
    #pragma unroll
    for (int k=0;k<64;k+=4){
      c0_ += hm[k]*W2[j*64+k];    c1 += hm[k+1]*W2[j*64+k+1];
      c2 += hm[k+2]*W2[j*64+k+2]; c3 += hm[k+3]*W2[j*64+k+3];
    }
    ctx[b*64+j] = (c0_+c1)+(c2+c3);
  }
}

// ---------------- GRU x-part GEMM: gig[b*T][96] f16 ----------------
__global__ __launch_bounds__(128) void k_gigru(
    const float* __restrict__ x_comp, const float* __restrict__ rain_f,
    const float* __restrict__ rain_b,
    const float* __restrict__ Wih, const float* __restrict__ bih,
    unsigned short* __restrict__ gig)
{
  __shared__ uint32_t WT[48][98];
  __shared__ __align__(16) uint32_t us[8][48];
  const int tid = threadIdx.x;
  for (int idx = tid; idx < 48*96; idx += 128){
    const int k = idx / 96, col = idx - k*96;
    WT[k][col] = pack2u_(Wih[(size_t)col*96 + 2*k], Wih[(size_t)col*96 + 2*k + 1]);
  }
  const float bias = (tid < 96) ? bih[tid] : 0.f;
  __syncthreads();
  const int NR = NB*NT;
  for (int r0 = blockIdx.x*8; r0 < NR; r0 += gridDim.x*8){
    __syncthreads();
    for (int idx = tid; idx < 8*48; idx += 128){
      const int r = idx / 48, w = idx - r*48;
      const size_t row = (size_t)r0 + r;
      const int i0 = 2*w, i1 = 2*w+1;
      const float a = (i0<32)? x_comp[row*32+i0] : (i0<64 ? rain_f[row*32+i0-32] : rain_b[row*32+i0-64]);
      const float c = (i1<32)? x_comp[row*32+i1] : (i1<64 ? rain_f[row*32+i1-32] : rain_b[row*32+i1-64]);
      us[r][w] = pack2u_(a, c);
    }
    __syncthreads();
    if (tid < 96){
      #pragma unroll
      for (int r=0;r<8;r++){
        const uint4* U = (const uint4*)us[r];
        float acc = bias;
        #pragma unroll
        for (int k4=0;k4<12;k4++){
          const uint4 u4 = U[k4];
          acc = dot2u_(u4.x, WT[4*k4][tid],   acc);
          acc = dot2u_(u4.y, WT[4*k4+1][tid], acc);
          acc = dot2u_(u4.z, WT[4*k4+2][tid], acc);
          acc = dot2u_(u4.w, WT[4*k4+3][tid], acc);
        }
        gig[((size_t)r0+r)*96 + tid] = f2h_(acc);
      }
    }
  }
}

// ---------------- GRU scan: 1 chain/block, grid 256, weights in LDS ----------------
__global__ __launch_bounds__(128) void k_gru(
    const unsigned short* __restrict__ gig, const int* __restrict__ lengths,
    const float* __restrict__ Whh, const float* __restrict__ bhh,
    float* __restrict__ ctx)
{
  __shared__ uint32_t Wg[96*20];
  __shared__ __align__(16) uint32_t hp[16];
  __shared__ float gpart[96];
  const int b = blockIdx.x;
  const int tid = threadIdx.x;
  for (int idx = tid; idx < 96*16; idx += 128){
    const int row = idx >> 4, k = idx & 15;
    Wg[row*20+k] = pack2u_(Whh[row*32+2*k], Whh[row*32+2*k+1]);
  }
  const float bh = (tid < 96) ? bhh[tid] : 0.f;
  int len = lengths[b]; if (len > NT) len = NT;
  float h = 0.f;
  if (tid < 16) hp[tid] = 0u;
  const unsigned short* gp = gig + (size_t)b*NT*96;
  float gir=0.f, giz=0.f, gin=0.f;
  if (tid < 32 && len > 0){ gir=h2f_(gp[tid]); giz=h2f_(gp[32+tid]); gin=h2f_(gp[64+tid]); }
  __syncthreads();
  for (int t=0; t<len; ++t){
    float nr=0.f, nz=0.f, nn=0.f;
    if (tid < 32 && t+1 < len){
      const unsigned short* gn = gp + (size_t)(t+1)*96;
      nr=h2f_(gn[tid]); nz=h2f_(gn[32+tid]); nn=h2f_(gn[64+tid]);
    }
    if (tid < 96){
      const uint4* W4 = (const uint4*)(Wg + tid*20);
      const uint4 w0=W4[0], w1=W4[1], w2=W4[2], w3=W4[3];
      const uint4* H4 = (const uint4*)hp;
      const uint4 H0=H4[0], H1=H4[1], H2=H4[2], H3=H4[3];
      float acc = bh;
      Q4(acc,w0,H0) Q4(acc,w1,H1) Q4(acc,w2,H2) Q4(acc,w3,H3)
      gpart[tid] = acc;
    }
    __syncthreads();
    if (tid < 32){
      const float r = sigmoidf_(gir + gpart[tid]);
      const float z = sigmoidf_(giz + gpart[32+tid]);
      const float n = tanhf_(gin + r*gpart[64+tid]);
      h = (1.0f - z)*n + z*h;
      gir=nr; giz=nz; gin=nn;
      const float pr = __shfl_xor(h, 1);
      if (!(tid & 1)) hp[tid>>1] = pack2u_(h, pr);
    }
    __syncthreads();
  }
  if (tid < 32) ctx[b*64 + 32 + tid] = h;
}

// ---------------- init: h0/c0, ctx-part of LSTM gates, hidden seeds ----------------
__global__ __launch_bounds__(256) void k_init(
    const float* __restrict__ ctx,
    const float* __restrict__ initW, const float* __restrict__ initb,
    const float* __restrict__ WihF, const float* __restrict__ bihF, const float* __restrict__ bhhF,
    const float* __restrict__ WihB, const float* __restrict__ bihB, const float* __restrict__ bhhB,
    float* __restrict__ h0, float* __restrict__ c0,
    float* __restrict__ cgF, float* __restrict__ cgB,
    float* __restrict__ hidden)
{
  const int b = blockIdx.x;
  const int j = threadIdx.x;
  __shared__ __align__(16) float cv[64];
  if (j < 64) cv[j] = ctx[b*64+j];
  __syncthreads();
  {
    float4 f = {bihF[j]+bhhF[j], 0.f, 0.f, 0.f};
    float4 g = {bihB[j]+bhhB[j], 0.f, 0.f, 0.f};
    #pragma unroll
    for (int q=0;q<16;q++){
      const float4 cvv = *(const float4*)&cv[4*q];
      const float4 wf = *(const float4*)(WihF + (size_t)j*128 + 64 + 4*q);
      const float4 wb = *(const float4*)(WihB + (size_t)j*128 + 64 + 4*q);
      f.x += cvv.x*wf.x; f.y += cvv.y*wf.y; f.z += cvv.z*wf.z; f.w += cvv.w*wf.w;
      g.x += cvv.x*wb.x; g.y += cvv.y*wb.y; g.z += cvv.z*wb.z; g.w += cvv.w*wb.w;
    }
    cgF[b*256+j] = (f.x+f.y)+(f.z+f.w);
    cgB[b*256+j] = (g.x+g.y)+(g.z+g.w);
  }
  if (j < 128){
    float4 a = {initb[j], 0.f, 0.f, 0.f};
    #pragma unroll
    for (int q=0;q<16;q++){
      const float4 cvv = *(const float4*)&cv[4*q];
      const float4 w  = *(const float4*)(initW + (size_t)j*64 + 4*q);
      a.x += cvv.x*w.x; a.y += cvv.y*w.y; a.z += cvv.z*w.z; a.w += cvv.w*w.w;
    }
    float hv = (a.x+a.y)+(a.z+a.w);
    h0[b*128+j] = hv;
    c0[b*128+j] = tanhf_(hv);
    if (j < 64) hidden[(size_t)b*NT*128 + j] = hv;                                // fwd seed t=0
    else        hidden[(size_t)b*NT*128 + (size_t)(NT-1)*128 + 64 + (j-64)] = hv; // bwd seed t=T-1
  }
}

// ---------------- LSTM scan: MFMA, weights resident in register A-fragments ----------------
__global__ __launch_bounds__(512,2) void k_lstm(
    const float* __restrict__ x_comp, const float* __restrict__ masks,
    const float* __restrict__ WihF, const float* __restrict__ WhhF,
    const float* __restrict__ WihB, const float* __restrict__ WhhB,
    const float* __restrict__ cgF, const float* __restrict__ cgB,
    const float* __restrict__ h0, const float* __restrict__ c0,
    const int* __restrict__ lengths,
    float* __restrict__ hidden)
{
  __shared__ __align__(16) _Float16 ubuf[2][64];
  __shared__ __align__(16) _Float16 hbuf[64];
  __shared__ __align__(16) float gbuf[256];
  const int b = blockIdx.x, dir = blockIdx.y;
  const int tid = threadIdx.x;
  const int l = tid & 63, wv = tid >> 6;
  const int m0 = wv * 32;
  const int arow = l & 15, ak = (l >> 4) * 8;
  const float* Wih = dir ? WihB : WihF;
  const float* Whh = dir ? WhhB : WhhF;
  f16x8 AX00, AX01, AX10, AX11, AH00, AH01, AH10, AH11;
  #define LDFRAG(dst, base, ld, row, kk) { \
    const float* p_ = (base) + (size_t)(row)*(ld) + (kk); \
    const float4 v0_ = *(const float4*)p_; const float4 v1_ = *(const float4*)(p_+4); \
    f16x8 t_; t_[0]=(_Float16)v0_.x; t_[1]=(_Float16)v0_.y; t_[2]=(_Float16)v0_.z; t_[3]=(_Float16)v0_.w; \
    t_[4]=(_Float16)v1_.x; t_[5]=(_Float16)v1_.y; t_[6]=(_Float16)v1_.z; t_[7]=(_Float16)v1_.w; dst = t_; }
  LDFRAG(AX00, Wih, 128, m0+arow,    ak)
  LDFRAG(AX01, Wih, 128, m0+arow,    32+ak)
  LDFRAG(AX10, Wih, 128, m0+16+arow, ak)
  LDFRAG(AX11, Wih, 128, m0+16+arow, 32+ak)
  LDFRAG(AH00, Whh, 64,  m0+arow,    ak)
  LDFRAG(AH01, Whh, 64,  m0+arow,    32+ak)
  LDFRAG(AH10, Whh, 64,  m0+16+arow, ak)
  LDFRAG(AH11, Whh, 64,  m0+16+arow, 32+ak)
  #undef LDFRAG
  const float* cgp = (dir ? cgB : cgF) + (size_t)b*256;
  const int crow = (l >> 4) * 4;
  const f32x4 cg0 = *(const f32x4*)(cgp + m0 + crow);
  const f32x4 cg1 = *(const f32x4*)(cgp + m0 + 16 + crow);
  asm volatile("" ::: "memory");
  const int len = lengths[b];
  int nsteps = NT-1;
  if (dir == 0){ int e = len-1; if (e<0) e=0; if (e<nsteps) nsteps = e; }
  const float* xc = x_comp + (size_t)b*NT*NV;
  const float* mk = masks  + (size_t)b*NT*NV;
  float* hout = hidden + (size_t)b*NT*128 + dir*64;
  float cst = 0.f;
  if (tid < 64){
    const float hv = h0[(size_t)b*128 + dir*64 + tid];
    cst            = c0[(size_t)b*128 + dir*64 + tid];
    hbuf[tid] = (_Float16)hv;
  }
  if (tid >= 64 && tid < 96 && nsteps > 0){
    const int u = tid - 64;
    const int t0 = dir ? NT-1 : 0;
    const float2 v = (u<16) ? *(const float2*)(xc + t0*NV + 2*u)
                            : *(const float2*)(mk + t0*NV + 2*(u-16));
    ubuf[0][2*u] = (_Float16)v.x; ubuf[0][2*u+1] = (_Float16)v.y;
  }
  __syncthreads();
  for (int s=0; s<nsteps; ++s){
    const int cur = s & 1;
    float2 pre = {0.f, 0.f};
    const bool dopf = (tid >= 64 && tid < 96 && s+1 < nsteps);
    if (dopf){
      const int u = tid - 64;
      const int tn = dir ? (NT-2-s) : (s+1);
      pre = (u<16) ? *(const float2*)(xc + tn*NV + 2*u)
                   : *(const float2*)(mk + tn*NV + 2*(u-16));
    }
    const f16x8 bu0 = *(const f16x8*)&ubuf[cur][ak];
    const f16x8 bu1 = *(const f16x8*)&ubuf[cur][32+ak];
    const f16x8 bh0 = *(const f16x8*)&hbuf[ak];
    const f16x8 bh1 = *(const f16x8*)&hbuf[32+ak];
    f32x4 a0 = cg0, a1 = cg1;
    a0 = __builtin_amdgcn_mfma_f32_16x16x32_f16(AX00, bu0, a0, 0, 0, 0);
    a0 = __builtin_amdgcn_mfma_f32_16x16x32_f16(AX01, bu1, a0, 0, 0, 0);
    a0 = __builtin_amdgcn_mfma_f32_16x16x32_f16(AH00, bh0, a0, 0, 0, 0);
    a0 = __builtin_amdgcn_mfma_f32_16x16x32_f16(AH01, bh1, a0, 0, 0, 0);
    a1 = __builtin_amdgcn_mfma_f32_16x16x32_f16(AX10, bu0, a1, 0, 0, 0);
    a1 = __builtin_amdgcn_mfma_f32_16x16x32_f16(AX11, bu1, a1, 0, 0, 0);
    a1 = __builtin_amdgcn_mfma_f32_16x16x32_f16(AH10, bh0, a1, 0, 0, 0);
    a1 = __builtin_amdgcn_mfma_f32_16x16x32_f16(AH11, bh1, a1, 0, 0, 0);
    if ((l & 15) == 0){
      *(f32x4*)&gbuf[m0 + crow]      = a0;
      *(f32x4*)&gbuf[m0 + 16 + crow] = a1;
    }
    if (dopf){
      const int u = tid - 64;
      ubuf[cur^1][2*u]   = (_Float16)pre.x;
      ubuf[cur^1][2*u+1] = (_Float16)pre.y;
    }
    __syncthreads();
    if (tid < 64){
      const float gi = gbuf[tid], gf = gbuf[64+tid], gg = gbuf[128+tid], go = gbuf[192+tid];
      cst = sigmoidf_(gf)*cst + sigmoidf_(gi)*tanhf_(gg);
      const float hh = sigmoidf_(go)*tanhf_(cst);
      const int outt = dir ? (NT-2-s) : (s+1);
      hout[(size_t)outt*128 + tid] = hh;
      hbuf[tid] = (_Float16)hh;
    }
    __syncthreads();
  }
}

// ---------------- feature-regression: MFMA, Wm/nl1 resident in A-fragments ----------------
// Per 16-row group: P1 hid[1024x16] = Wm[1024x32] @ X[32x16] (64 MFMA, 8/wave),
// relu+bias -> LDS hidb[i][n][h] f16; P2 zh[32x512] = nl1 @ relu(hid) (cols c = i*16+n),
// nl2 reduce via shfl_xor(16,32); coalesced output via fout staging.
__global__ __launch_bounds__(512,1) void k_feat(
    const float* __restrict__ x_comp,
    const float* __restrict__ feat_W, const float* __restrict__ feat_b,
    const float* __restrict__ nl1_W, const float* __restrict__ nl1_b,
    const float* __restrict__ nl2_W, const float* __restrict__ nl2_b,
    float* __restrict__ feat_imp)
{
  __shared__ __align__(16) _Float16 xbuf[16*32];        // [n][v]
  __shared__ __align__(16) _Float16 hidb[32*16*32];     // [i][n][h]  32 KB
  __shared__ __align__(16) float fbl[1024];             // feat_b
  __shared__ float fout[16*33];                         // [n][i] padded
  const int tid = threadIdx.x;
  const int l = tid & 63, wv = tid >> 6;
  const int fr = l >> 4, fc = l & 15;
  const int ak = fr * 8;
  // P1 A-frags: m-tiles wv*8 .. wv*8+7 of masked Wm[m=i*32+h][v]
  f16x8 WA0, WA1, WA2, WA3, WA4, WA5, WA6, WA7;
  #define LDWA(dst, q) { \
    const int m_ = (wv*8 + (q))*16 + fc; \
    const int i_ = m_ >> 5; \
    const float* s_ = feat_W + (size_t)m_*32 + ak; \
    f16x8 t_; \
    _Pragma("unroll") \
    for (int e_=0; e_<8; ++e_){ \
      float w_ = s_[e_]; \
      if (ak + e_ == i_) w_ = 0.f; \
      t_[e_] = (_Float16)w_; } \
    dst = t_; }
  LDWA(WA0,0) LDWA(WA1,1) LDWA(WA2,2) LDWA(WA3,3)
  LDWA(WA4,4) LDWA(WA5,5) LDWA(WA6,6) LDWA(WA7,7)
  #undef LDWA
  // P2 A-frags: nl1_W[h'][h], m-tiles 0,1
  f16x8 NA0, NA1;
  {
    f16x8 t0, t1;
    #pragma unroll
    for (int e=0;e<8;e++){
      t0[e] = (_Float16)nl1_W[(fc)*32 + ak + e];
      t1[e] = (_Float16)nl1_W[(16 + fc)*32 + ak + e];
    }
    NA0 = t0; NA1 = t1;
  }
  f32x4 n1b0, n1b1;
  float n2w0[4], n2w1[4];
  #pragma unroll
  for (int j=0;j<4;j++){
    n1b0[j] = nl1_b[fr*4+j];
    n1b1[j] = nl1_b[16 + fr*4+j];
    n2w0[j] = nl2_W[fr*4+j];
    n2w1[j] = nl2_W[16 + fr*4+j];
  }
  const float n2b = nl2_b[0];
  for (int idx = tid; idx < 1024; idx += 512) fbl[idx] = feat_b[idx];
  asm volatile("" ::: "memory");
  const int NG = (NB*NT)/16;
  for (int g = blockIdx.x; g < NG; g += gridDim.x){
    const size_t r0 = (size_t)g*16;
    __syncthreads();
    {
      const int n = tid >> 5, v = tid & 31;
      xbuf[n*32+v] = (_Float16)x_comp[(r0+n)*32 + v];
    }
    __syncthreads();
    // P1
    const f16x8 xB = *(const f16x8*)&xbuf[fc*32 + ak];
    #pragma unroll
    for (int q=0;q<8;q++){
      const int mt = wv*8 + q;
      f32x4 acc = {0.f,0.f,0.f,0.f};
      const f16x8 WA = (q==0)?WA0:(q==1)?WA1:(q==2)?WA2:(q==3)?WA3:(q==4)?WA4:(q==5)?WA5:(q==6)?WA6:WA7;
      acc = __builtin_amdgcn_mfma_f32_16x16x32_f16(WA, xB, acc, 0, 0, 0);
      const int mbase = mt*16 + fr*4;
      const f32x4 fb4 = *(const f32x4*)&fbl[mbase];
      #pragma unroll
      for (int jj=0;jj<4;jj+=2){
        const int m0_ = mbase + jj;
        const int i_ = m0_ >> 5, h_ = m0_ & 31;
        const float v0_ = fmaxf(acc[jj]   + fb4[jj],   0.f);
        const float v1_ = fmaxf(acc[jj+1] + fb4[jj+1], 0.f);
        h2_t p; p.x = (_Float16)v0_; p.y = (_Float16)v1_;
        *(h2_t*)&hidb[(i_*16+fc)*32 + h_] = p;
      }
    }
    __syncthreads();
    // P2: wave handles n-tiles (i values) 4wv..4wv+3
    float outv[4];
    #pragma unroll
    for (int q=0;q<4;q++){
      const int nt = wv*4 + q;
      const f16x8 hB = *(const f16x8*)&hidb[(nt*16+fc)*32 + ak];
      f32x4 z0 = n1b0, z1 = n1b1;
      z0 = __builtin_amdgcn_mfma_f32_16x16x32_f16(NA0, hB, z0, 0, 0, 0);
      z1 = __builtin_amdgcn_mfma_f32_16x16x32_f16(NA1, hB, z1, 0, 0, 0);
      float s = 0.f;
      #pragma unroll
      for (int j=0;j<4;j++){
        s += fmaxf(z0[j], 0.f)*n2w0[j];
        s += fmaxf(z1[j], 0.f)*n2w1[j];
      }
      s += __shfl_xor(s, 16);
      s += __shfl_xor(s, 32);
      outv[q] = s;
    }
    if (fr == 0){
      #pragma unroll
      for (int q=0;q<4;q++) fout[fc*33 + wv*4 + q] = outv[q] + n2b;
    }
    __syncthreads();
    feat_imp[r0*32 + tid] = fout[(tid>>5)*33 + (tid&31)];
  }
}

// ---------------- rnn_imp GEMM + fuse + final: LDS f16 rimp ----------------
__global__ __launch_bounds__(512) void k_final(
    const float* __restrict__ values, const float* __restrict__ masks,
    const float* __restrict__ feat_imp, const float* __restrict__ hidden,
    const float* __restrict__ rimp_W, const float* __restrict__ rimp_b,
    const float* __restrict__ fuse_W, const float* __restrict__ fuse_b,
    const int* __restrict__ lengths, float* __restrict__ out)
{
  const int tid = threadIdx.x;
  const int v = tid & 31;
  const int grp = (tid >> 5) & 7;
  const int half = tid >> 8;
  __shared__ uint32_t rpT[64][32];
  __shared__ __align__(16) uint32_t hrowp[8][64];
  __shared__ float rpart[8][32];
  __shared__ float bpart[8][32];
  for (int idx = tid; idx < 64*32; idx += 512){
    const int k = idx >> 5, vv = idx & 31;
    rpT[k][vv] = pack2u_(rimp_W[(size_t)vv*128 + 2*k], rimp_W[(size_t)vv*128 + 2*k+1]);
  }
  const float4* F4 = (const float4*)(fuse_W + (size_t)v*64 + 32);
  float fconst = 0.f;
  if (!half){
    fconst = fuse_b[v];
    #pragma unroll
    for (int q=0;q<8;q++){
      const float4 fw = *(const float4*)(fuse_W + (size_t)v*64 + 4*q);
      fconst += (fw.x+fw.y)+(fw.z+fw.w);
    }
  }
  const float rbias = rimp_b[v];
  __syncthreads();
  const int NOCT = (NB*NT)/8;
  for (int oc = blockIdx.x; oc < NOCT; oc += gridDim.x){
    const size_t base = (size_t)oc*8;
    __syncthreads();
    if (tid < 256){
      const float4 hv = ((const float4*)(hidden + base*128))[tid];
      const int row = tid >> 5;
      const int w0 = (tid & 31) << 1;
      hrowp[row][w0]   = pack2u_(hv.x, hv.y);
      hrowp[row][w0+1] = pack2u_(hv.z, hv.w);
    }
    __syncthreads();
    const size_t r = base + grp;
    float a = half ? 0.f : rbias;
    {
      const uint4* hp4 = (const uint4*)&hrowp[grp][half*32];
      #pragma unroll
      for (int c4=0;c4<8;c4++){
        const uint4 H = hp4[c4];
        a = dot2u_(H.x, rpT[half*32 + 4*c4][v],     a);
        a = dot2u_(H.y, rpT[half*32 + 4*c4 + 1][v], a);
        a = dot2u_(H.z, rpT[half*32 + 4*c4 + 2][v], a);
        a = dot2u_(H.w, rpT[half*32 + 4*c4 + 3][v], a);
      }
    }
    if (half){
      rpart[grp][v] = a;
      const float* mrow = masks + r*32;
      float m0=0,m1=0,m2=0,m3=0;
      #pragma unroll
      for (int q=0;q<8;q++){
        const float4 mv = *(const float4*)(mrow + 4*q);
        const float4 fv = F4[q];
        m0 = fmaf(mv.x, fv.x, m0); m1 = fmaf(mv.y, fv.y, m1);
        m2 = fmaf(mv.z, fv.z, m2); m3 = fmaf(mv.w, fv.w, m3);
      }
      bpart[grp][v] = (m0+m1)+(m2+m3);
    }
    __syncthreads();
    if (!half){
      const int bb = (int)(r >> 9);
      const int t  = (int)(r & 511);
      const int len = lengths[bb];
      const float rimp = a + rpart[grp][v];
      const float beta = sigmoidf_(fconst + bpart[grp][v]);
      const float fi = feat_imp[r*32+v];
      const float m  = masks[r*32+v];
      const float val= values[r*32+v];
      const float fz = beta*fi + (1.0f-beta)*rimp;
      const float o = m*val + (1.0f-m)*fz;
      out[r*32+v] = (t < len) ? o : 0.0f;
    }
  }
}

extern "C" void kernel_launch(void* const* d_in, const int* in_sizes, int n_in,
                              void* d_out, int out_size, void* d_ws, size_t ws_size,
                              hipStream_t stream) {
  const float* values   = (const float*)d_in[0];
  const float* masks    = (const float*)d_in[1];
  const float* rain_f   = (const float*)d_in[2];
  const float* rain_b   = (const float*)d_in[3];
  const float* cmlp_W1  = (const float*)d_in[4];
  const float* cmlp_b1  = (const float*)d_in[5];
  const float* cmlp_W2  = (const float*)d_in[6];
  const float* cmlp_b2  = (const float*)d_in[7];
  const float* gru_Wih  = (const float*)d_in[8];
  const float* gru_Whh  = (const float*)d_in[9];
  const float* gru_bih  = (const float*)d_in[10];
  const float* gru_bhh  = (const float*)d_in[11];
  const float* init_W   = (const float*)d_in[12];
  const float* init_b   = (const float*)d_in[13];
  const float* lstmf_Wih= (const float*)d_in[14];
  const float* lstmf_Whh= (const float*)d_in[15];
  const float* lstmf_bih= (const float*)d_in[16];
  const float* lstmf_bhh= (const float*)d_in[17];
  const float* lstmb_Wih= (const float*)d_in[18];
  const float* lstmb_Whh= (const float*)d_in[19];
  const float* lstmb_bih= (const float*)d_in[20];
  const float* lstmb_bhh= (const float*)d_in[21];
  const float* rimp_W   = (const float*)d_in[22];
  const float* rimp_b   = (const float*)d_in[23];
  const float* feat_W   = (const float*)d_in[24];
  const float* feat_b   = (const float*)d_in[25];
  const float* nl1_W    = (const float*)d_in[26];
  const float* nl1_b    = (const float*)d_in[27];
  const float* nl2_W    = (const float*)d_in[28];
  const float* nl2_b    = (const float*)d_in[29];
  const float* fuse_W   = (const float*)d_in[30];
  const float* fuse_b   = (const float*)d_in[31];
  const int*   lengths  = (const int*)d_in[32];
  float* out = (float*)d_out;

  float* ws       = (float*)d_ws;
  float* x_comp   = ws;                                   // B*T*V
  float* stats    = x_comp + (size_t)NB*NT*NV;            // B*97
  float* ctx      = stats + NB*97;                        // B*64
  float* h0       = ctx + NB*64;                          // B*128
  float* c0      = h0 + NB*128;                           // B*128
  float* cgF      = c0 + NB*128;                          // B*256
  float* cgB      = cgF + NB*256;                         // B*256
  float* hidden   = cgB + NB*256;                         // B*T*128
  float* feat_imp = hidden + (size_t)NB*NT*128;           // B*T*V
  unsigned short* gig = (unsigned short*)(feat_imp + (size_t)NB*NT*NV); // B*T*96 f16
  // total ~127 MB

  k_stats<<<NB, 256, 0, stream>>>(values, masks, lengths, x_comp, stats);
  k_gigru<<<1024, 128, 0, stream>>>(x_comp, rain_f, rain_b, gru_Wih, gru_bih, gig);
  k_cmlp<<<NB, 64, 0, stream>>>(stats, cmlp_W1, cmlp_b1, cmlp_W2, cmlp_b2, ctx);
  k_gru<<<NB, 128, 0, stream>>>(gig, lengths, gru_Whh, gru_bhh, ctx);
  k_init<<<NB, 256, 0, stream>>>(ctx, init_W, init_b,
                                 lstmf_Wih, lstmf_bih, lstmf_bhh,
                                 lstmb_Wih, lstmb_bih, lstmb_bhh,
                                 h0, c0, cgF, cgB, hidden);
  dim3 lgrid(NB, 2);
  k_lstm<<<lgrid, 512, 0, stream>>>(x_comp, masks,
                                    lstmf_Wih, lstmf_Whh, lstmb_Wih, lstmb_Whh,
                                    cgF, cgB, h0, c0, lengths, hidden);
  k_feat<<<256, 512, 0, stream>>>(x_comp, feat_W, feat_b, nl1_W, nl1_b, nl2_W, nl2_b, feat_imp);
  k_final<<<2048, 512, 0, stream>>>(values, masks, feat_imp, hidden,
                                    rimp_W, rimp_b, fuse_W, fuse_b, lengths, out);
}